// Round 11
// baseline (549.526 us; speedup 1.0000x reference)
//
#include <hip/hip_runtime.h>
#include <math.h>

#define DEVINL __device__ __forceinline__

constexpr int B_ = 64;
constexpr int N_ = 3136;
constexpr int C_ = 64;        // DIM
constexpr int NG = 49;        // N_grid
constexpr int NSAMP = 784;    // SAMPLE_NUM
constexpr int ND = NG + NSAMP;     // 833
constexpr int NREST = N_ - NG;     // 3087
constexpr int H_ = 56, W_ = 56;
constexpr int HW = H_ * W_;        // 3136
constexpr int BHW = B_ * HW;       // 200704
constexpr int NS = 14 * 14;        // 196 kv tokens
constexpr int KPAD = 224;          // 196 padded to 7*32
constexpr int NROW = B_ * ND;      // 53312
constexpr float LN_EPS = 1e-5f;
constexpr float EPS6 = 1e-6f;

typedef __attribute__((ext_vector_type(8))) short short8;
typedef __attribute__((ext_vector_type(4))) float f32x4;

DEVINL unsigned short f2bf(float f) {
  unsigned int u = __float_as_uint(f);
  unsigned int r = u + 0x7FFFu + ((u >> 16) & 1u);
  return (unsigned short)(r >> 16);
}

// Fast exact-GELU: erf via Abramowitz-Stegun 7.1.26 (|err| <= 1.5e-7).
DEVINL float gelu_fast(float v) {
  float x = v * 0.70710678118654752f;
  float ax = fabsf(x);
  float t = 1.f / fmaf(0.3275911f, ax, 1.f);
  float poly = t * fmaf(t, fmaf(t, fmaf(t, fmaf(t, 1.061405429f, -1.453152027f),
                        1.421413741f), -0.284496736f), 0.254829592f);
  float e = 1.f - poly * __expf(-x * x);
  float erfv = copysignf(e, x);
  return 0.5f * v * (1.f + erfv);
}

// ---------------------------------------------------------------------------
// K1: conf scores in FP64 (discrete top-k decision must match f64 np ref)
// ---------------------------------------------------------------------------
__global__ __launch_bounds__(256) void k_conf(
    const float* __restrict__ x, const float* __restrict__ ng, const float* __restrict__ nb,
    const float* __restrict__ cw, const float* __restrict__ cb,
    const float* __restrict__ nu, double* __restrict__ scores) {
  int t = blockIdx.x * 256 + threadIdx.x;
  if (t >= B_ * N_) return;
  int b = t / N_, n = t - b * N_;
  if (n < NG) return;
  const float4* row = (const float4*)(x + (size_t)t * C_);
  float v[C_];
#pragma unroll
  for (int i = 0; i < 16; ++i) {
    float4 r = row[i];
    v[4*i] = r.x; v[4*i+1] = r.y; v[4*i+2] = r.z; v[4*i+3] = r.w;
  }
  double sd = 0.0;
#pragma unroll
  for (int i = 0; i < C_; ++i) sd += (double)v[i];
  double md = sd * (1.0/64.0);
  double vd = 0.0;
#pragma unroll
  for (int i = 0; i < C_; ++i) { double d = (double)v[i] - md; vd += d * d; }
  vd *= (1.0/64.0);
  double rsd = 1.0 / sqrt(vd + 1e-5);
  double conf = (double)cb[0];
#pragma unroll
  for (int i = 0; i < C_; ++i) {
    double xnv = ((double)v[i] - md) * rsd;
    conf += (xnv * (double)ng[i] + (double)nb[i]) * (double)cw[i];
  }
  double u = (double)nu[(size_t)b * NREST + (n - NG)];
  double noise = -log(-log(u + 1e-6) + 1e-6);
  scores[(size_t)b * NREST + (n - NG)] = conf + noise;
}

// ---------------------------------------------------------------------------
// K2: exact top-784 via counting-sort rank. One block per batch.
// ---------------------------------------------------------------------------
constexpr int NB = 2048;

__global__ __launch_bounds__(256) void k_topk2(const double* __restrict__ scores,
                                               int* __restrict__ idx) {
  __shared__ double sk[NREST];              // 24,696 B
  __shared__ int hist[NB];                  //  8,192 B
  __shared__ int bstart[NB];                //  8,192 B
  __shared__ int fill[NB];                  //  8,192 B
  __shared__ unsigned short order[NREST];   //  6,174 B
  __shared__ float redmin[256], redmax[256];//  2,048 B
  __shared__ int scanbuf[256];              //  1,024 B   (~58.5 KB total)
  int b = blockIdx.x, tid = threadIdx.x;
  const double* sc = scores + (size_t)b * NREST;
  float lmin = 3.4e38f, lmax = -3.4e38f;
  for (int i = tid; i < NREST; i += 256) {
    double d = sc[i];
    sk[i] = d;
    float f = (float)d;
    lmin = fminf(lmin, f); lmax = fmaxf(lmax, f);
  }
  for (int i = tid; i < NB; i += 256) hist[i] = 0;
  redmin[tid] = lmin; redmax[tid] = lmax;
  __syncthreads();
  for (int s = 128; s > 0; s >>= 1) {
    if (tid < s) {
      redmin[tid] = fminf(redmin[tid], redmin[tid + s]);
      redmax[tid] = fmaxf(redmax[tid], redmax[tid + s]);
    }
    __syncthreads();
  }
  float fmn = redmin[0];
  float scale = (float)NB / fmaxf(redmax[0] - fmn, 1e-30f);
  // histogram
  for (int i = tid; i < NREST; i += 256) {
    float f = (float)sk[i];
    int bn = (int)((f - fmn) * scale);
    bn = bn < 0 ? 0 : (bn > NB - 1 ? NB - 1 : bn);
    atomicAdd(&hist[bn], 1);
  }
  __syncthreads();
  // suffix scan: bstart[bin] = sum over strictly-higher bins.
  int base = tid * 8;          // this thread owns bins [base, base+8)
  int s_t = 0;
#pragma unroll
  for (int i = 0; i < 8; ++i) s_t += hist[base + i];
  scanbuf[tid] = s_t;
  __syncthreads();
  int val = s_t;
  for (int off = 1; off < 256; off <<= 1) {
    int other = (tid + off < 256) ? scanbuf[tid + off] : 0;
    __syncthreads();
    val += other;
    scanbuf[tid] = val;
    __syncthreads();
  }
  int run = val - s_t;         // sum over threads t' > tid
#pragma unroll
  for (int i = 7; i >= 0; --i) {
    bstart[base + i] = run;
    run += hist[base + i];
  }
  __syncthreads();
  for (int i = tid; i < NB; i += 256) fill[i] = bstart[i];
  __syncthreads();
  // scatter element ids into bin-grouped order[]
  for (int i = tid; i < NREST; i += 256) {
    float f = (float)sk[i];
    int bn = (int)((f - fmn) * scale);
    bn = bn < 0 ? 0 : (bn > NB - 1 ? NB - 1 : bn);
    int pos = atomicAdd(&fill[bn], 1);
    order[pos] = (unsigned short)i;
  }
  __syncthreads();
  // exact rank = bstart[bin] + within-bin f64 rank; write winners
  for (int i = tid; i < NREST; i += 256) {
    double ke = sk[i];
    float f = (float)ke;
    int bn = (int)((f - fmn) * scale);
    bn = bn < 0 ? 0 : (bn > NB - 1 ? NB - 1 : bn);
    int st = bstart[bn], m = hist[bn];
    int r = st;
    for (int p = st; p < st + m; ++p) {
      int j = order[p];
      double kj = sk[j];
      r += (int)((kj > ke) | ((kj == ke) & (j < i)));
    }
    if (r < NSAMP) idx[(size_t)b * NSAMP + r] = i;
  }
}

// ---------------------------------------------------------------------------
// K3: gather x_down/pos_down rows; LayerNorm(x_down, norm1) -> xn
// ---------------------------------------------------------------------------
__global__ __launch_bounds__(256) void k_gather_ln(
    const float* __restrict__ x, const float* __restrict__ pos, const int* __restrict__ idx,
    const float* __restrict__ n1g, const float* __restrict__ n1b,
    float* __restrict__ xd, float* __restrict__ xn, float* __restrict__ pd) {
  int t = blockIdx.x * 256 + threadIdx.x;
  if (t >= B_ * ND) return;
  int b = t / ND, r = t - b * ND;
  int srcn = (r < NG) ? r : (NG + idx[(size_t)b * NSAMP + (r - NG)]);
  const float4* row = (const float4*)(x + ((size_t)b * N_ + srcn) * C_);
  float4* xdr = (float4*)(xd + (size_t)t * C_);
  float v[C_];
  float s = 0.f, ss = 0.f;
#pragma unroll
  for (int i = 0; i < 16; ++i) {
    float4 rr = row[i];
    xdr[i] = rr;
    v[4*i] = rr.x; v[4*i+1] = rr.y; v[4*i+2] = rr.z; v[4*i+3] = rr.w;
    s += rr.x + rr.y + rr.z + rr.w;
    ss += rr.x*rr.x + rr.y*rr.y + rr.z*rr.z + rr.w*rr.w;
  }
  float m = s * (1.f/64.f);
  float var = ss * (1.f/64.f) - m*m;
  float rs = rsqrtf(var + LN_EPS);
#pragma unroll
  for (int i = 0; i < C_; ++i)
    xn[(size_t)t * C_ + i] = (v[i] - m) * rs * n1g[i] + n1b[i];
  pd[(size_t)2*t]   = pos[((size_t)b * N_ + srcn) * 2];
  pd[(size_t)2*t+1] = pos[((size_t)b * N_ + srcn) * 2 + 1];
}

// ---------------------------------------------------------------------------
// K4a: build per-pixel token linked lists (1 atomicExch per token).
// ---------------------------------------------------------------------------
__global__ __launch_bounds__(256) void k_link(
    const float* __restrict__ pos, int* __restrict__ head, int* __restrict__ next) {
  int tok = blockIdx.x * 256 + threadIdx.x;
  if (tok >= B_ * N_) return;
  int b = tok / N_;
  double px = fmin(fmax((double)pos[(size_t)2*tok],   0.0), 1.0) * (double)(W_ - 1);
  double py = fmin(fmax((double)pos[(size_t)2*tok+1], 0.0), 1.0) * (double)(H_ - 1);
  int xi = (int)rint(px), yi = (int)rint(py);
  int p = b * HW + yi * W_ + xi;
  next[tok] = atomicExch(&head[p], tok);
}

// ---------------------------------------------------------------------------
// K4b: gather-accumulate. One WAVE per pixel, lane = channel.
// ---------------------------------------------------------------------------
__global__ __launch_bounds__(256) void k_accum(
    const float* __restrict__ x, const float* __restrict__ n1g, const float* __restrict__ n1b,
    const int* __restrict__ head, const int* __restrict__ next, float* __restrict__ S) {
  int gt = blockIdx.x * 256 + threadIdx.x;
  int p = gt >> 6, lane = gt & 63;
  if (p >= B_ * HW) return;
  float g = n1g[lane], bb = n1b[lane];
  float acc = 0.f, cnt = 0.f;
  int tok = head[p];
  while (tok >= 0) {
    float v = x[(size_t)tok * C_ + lane];
    float s = v, ss = v * v;
#pragma unroll
    for (int m = 32; m > 0; m >>= 1) {
      s += __shfl_xor(s, m);
      ss += __shfl_xor(ss, m);
    }
    float mean = s * (1.f/64.f);
    float var = ss * (1.f/64.f) - mean * mean;
    float rs = rsqrtf(var + LN_EPS);
    acc += (v - mean) * rs * g + bb;
    cnt += 1.f;
    tok = next[tok];
  }
  float* base = S + (size_t)p * 65;
  base[lane] = acc;
  if (lane == 0) base[64] = cnt;
}

// ---------------------------------------------------------------------------
// K5b: transpose S[p][65] -> channel planes T[b][c][HW] + mask plane M.
// ---------------------------------------------------------------------------
__global__ __launch_bounds__(256) void k_transpose(const float* __restrict__ S,
                                                   float* __restrict__ T,
                                                   float* __restrict__ M) {
  __shared__ float ls[64 * 65];
  int g0 = blockIdx.x * 64;            // global pixel base (batch-major)
  int b = g0 / HW, p0 = g0 - b * HW;
  const float4* src = (const float4*)(S + (size_t)g0 * 65);
  for (int i = threadIdx.x; i < (64 * 65) / 4; i += 256)
    *(float4*)&ls[i * 4] = src[i];
  __syncthreads();
  for (int i = threadIdx.x; i < 64 * 64; i += 256) {
    int c = i >> 6, px = i & 63;
    T[((size_t)(b * 64 + c)) * HW + p0 + px] = ls[px * 65 + c];
  }
  for (int i = threadIdx.x; i < 64; i += 256)
    M[(size_t)g0 + i] = ls[i * 65 + 64];
}

// ---------------------------------------------------------------------------
// K5a: per-pixel 3x3 coefficient planes, mask read from contiguous M plane.
// ---------------------------------------------------------------------------
__global__ __launch_bounds__(256) void k_coef(const float* __restrict__ M, float* __restrict__ Kc) {
  int t = blockIdx.x * 256 + threadIdx.x;
  if (t >= BHW) return;
  int b = t / HW, p = t - b * HW;
  int y = p / W_, x = p - y * W_;
  const float* Mb = M + (size_t)b * HW;
  const float e1 = 0.882496902584595f;   // exp(-1/8)
  const float e2 = 0.778800783071405f;   // exp(-1/4)
  const float Z = 1.f + 4.f * (e1 + e2);
  float m0 = Mb[p];
  float mb0 = m0 > 0.f ? 1.f : 0.f;
  float cfac = mb0 / (m0 + EPS6);
  float sc[9];
  float mi = 0.f;
  int q = 0;
#pragma unroll
  for (int dy = -1; dy <= 1; ++dy) {
#pragma unroll
    for (int dx = -1; dx <= 1; ++dx) {
      int ny = y + dy, nx = x + dx;
      bool in = (ny >= 0 && ny < H_ && nx >= 0 && nx < W_);
      float w = ((dx == 0 && dy == 0) ? 1.f : ((dx*dx + dy*dy) == 1 ? e1 : e2)) / Z;
      float mm = in ? Mb[ny * W_ + nx] : 0.f;
      float mb = mm > 0.f ? 1.f : 0.f;
      mi += w * mb;
      sc[q] = in ? (w * mb / (mm + EPS6)) : 0.f;
      ++q;
    }
  }
  float outer = (1.f - mb0) * ((mi > 0.f ? 1.f : 0.f) / (mi + EPS6));
#pragma unroll
  for (int qq = 0; qq < 9; ++qq) {
    float cq = outer * sc[qq];
    if (qq == 4) cq += cfac;
    Kc[(size_t)qq * BHW + t] = cq;
  }
}

// ---------------------------------------------------------------------------
// K5c: spatially-varying 3x3 conv on channel planes -> conv-patch layout P.
// ---------------------------------------------------------------------------
__global__ __launch_bounds__(256) void k_filter2(
    const float* __restrict__ T, const float* __restrict__ Kc, float* __restrict__ P) {
  int plane = blockIdx.x;              // b*64 + c
  int b = plane >> 6, c = plane & 63;
  int tid = threadIdx.x;
  const float* Tp = T + (size_t)plane * HW;
  const float* Kb = Kc + (size_t)b * HW;
  for (int p0 = 0; p0 < HW; p0 += 256) {
    int p = p0 + tid;
    if (p < HW) {
      int y = p / W_, x = p - y * W_;
      float acc = 0.f;
      int q = 0;
#pragma unroll
      for (int dy = -1; dy <= 1; ++dy) {
#pragma unroll
        for (int dx = -1; dx <= 1; ++dx) {
          int ny = y + dy; ny = ny < 0 ? 0 : (ny > H_ - 1 ? H_ - 1 : ny);
          int nx = x + dx; nx = nx < 0 ? 0 : (nx > W_ - 1 ? W_ - 1 : nx);
          acc += Kb[(size_t)q * BHW + p] * Tp[ny * W_ + nx];
          ++q;
        }
      }
      int j = (y >> 2) * 14 + (x >> 2);
      int colb = ((y & 3) << 2) + (x & 3);
      P[((size_t)(b * NS + j)) * 1024 + c * 16 + colb] = acc;
    }
  }
}

// ---------------------------------------------------------------------------
// K6: pack sr_w into chunk-contiguous bf16 B-frag layout for the conv GEMM.
// ---------------------------------------------------------------------------
__global__ __launch_bounds__(256) void k_wtp(const float* __restrict__ srw,
                                             unsigned short* __restrict__ Wcp) {
  int t = blockIdx.x * 256 + threadIdx.x;
  if (t >= 65536) return;
  int j = t & 7;
  int n = (t >> 3) & 63;        // co
  int s = (t >> 9) & 15;        // kc*4 + quad
  int ch = t >> 13;             // 0..7
  int k = ch * 128 + (s >> 2) * 32 + (s & 3) * 8 + j;
  int ci = k >> 4, r = k & 15;
  Wcp[t] = f2bf(srw[(((size_t)n * 64 + ci) << 4) + r]);
}

// ---------------------------------------------------------------------------
// K6b: pack fc1/fc2 weights into CHUNK-contiguous bf16 layouts
// ---------------------------------------------------------------------------
__global__ __launch_bounds__(256) void k_wpack(const float* __restrict__ W1, const float* __restrict__ W2,
    unsigned short* __restrict__ W1q, unsigned short* __restrict__ W2q) {
  int t = blockIdx.x * 256 + threadIdx.x;
  if (t >= 65536) return;
  {
    int j = t & 7;
    int nl = (t >> 3) & 63;
    int s = (t >> 9) & 15;       // kc*4 + quad
    int hh = t >> 13;            // 0..7
    int k = (s >> 2) * 32 + (s & 3) * 8 + j;
    int n = hh * 64 + nl;
    W1q[t] = f2bf(W1[(size_t)k * 512 + n]);
  }
  {
    int j = t & 7;
    int n = (t >> 3) & 127;
    int s = (t >> 10) & 7;       // kg*4 + quad
    int hh = t >> 13;            // 0..7
    int k = hh * 64 + (s >> 2) * 32 + (s & 3) * 8 + j;
    W2q[t] = f2bf(W2[(size_t)k * 128 + n]);
  }
}

// ---------------------------------------------------------------------------
// K-CONV: xs_n = LN64(P @ wt + sr_b) -- LN fused into epilogue.
// ---------------------------------------------------------------------------
__global__ __launch_bounds__(256) void k_conv(
    const float* __restrict__ P, const unsigned short* __restrict__ Wcp,
    const float* __restrict__ bias, const float* __restrict__ sg,
    const float* __restrict__ sb, float* __restrict__ xsn) {
  __shared__ __align__(16) unsigned short sA[64 * 128];
  __shared__ __align__(16) unsigned short sW[8192];
  int bm = blockIdx.x * 64;
  int tid = threadIdx.x;
  int wv = tid >> 6, lane = tid & 63, quad = lane >> 4, l16 = lane & 15;

  const short8* gw = (const short8*)Wcp;
  short8* dw = (short8*)sW;

  short8 rw[4];
  float4 fa[4][2];
#pragma unroll
  for (int i = 0; i < 4; ++i) rw[i] = gw[i * 256 + tid];
#pragma unroll
  for (int i = 0; i < 4; ++i) {
    int u = i * 256 + tid;
    int row = u >> 4, ck = u & 15;
    const float* src = P + (size_t)(bm + row) * 1024 + ck * 8;
    fa[i][0] = *(const float4*)src;
    fa[i][1] = *(const float4*)(src + 4);
  }

  f32x4 acc[4];
#pragma unroll
  for (int ct = 0; ct < 4; ++ct) acc[ct] = (f32x4){0.f, 0.f, 0.f, 0.f};

  for (int ch = 0; ch < 8; ++ch) {
#pragma unroll
    for (int i = 0; i < 4; ++i) {
      dw[i * 256 + tid] = rw[i];
      int u = i * 256 + tid;
      int row = u >> 4, ck = u & 15;
      short8 p;
      p[0]=(short)f2bf(fa[i][0].x); p[1]=(short)f2bf(fa[i][0].y);
      p[2]=(short)f2bf(fa[i][0].z); p[3]=(short)f2bf(fa[i][0].w);
      p[4]=(short)f2bf(fa[i][1].x); p[5]=(short)f2bf(fa[i][1].y);
      p[6]=(short)f2bf(fa[i][1].z); p[7]=(short)f2bf(fa[i][1].w);
      *(short8*)&sA[row * 128 + (((ck ^ row) & 15) << 3)] = p;
    }
    __syncthreads();   // chunk visible
    if (ch < 7) {
      int wbase = (ch + 1) * 1024;
#pragma unroll
      for (int i = 0; i < 4; ++i) rw[i] = gw[wbase + i * 256 + tid];
#pragma unroll
      for (int i = 0; i < 4; ++i) {
        int u = i * 256 + tid;
        int row = u >> 4, ck = u & 15;
        const float* src = P + (size_t)(bm + row) * 1024 + (ch + 1) * 128 + ck * 8;
        fa[i][0] = *(const float4*)src;
        fa[i][1] = *(const float4*)(src + 4);
      }
    }
#pragma unroll
    for (int kc = 0; kc < 4; ++kc) {
      int row = wv * 16 + l16;
      int ck = kc * 4 + quad;
      short8 af = *(const short8*)&sA[row * 128 + (((ck ^ row) & 15) << 3)];
      int s = kc * 4 + quad;
#pragma unroll
      for (int ct = 0; ct < 4; ++ct) {
        short8 bf = *(const short8*)&sW[(s * 64 + ct * 16 + l16) << 3];
        acc[ct] = __builtin_amdgcn_mfma_f32_16x16x32_bf16(af, bf, acc[ct], 0, 0, 0);
      }
    }
    __syncthreads();   // all waves done reading before next commit
  }
  // epilogue: + bias, fused LN64, write xs_n
  float vv[4][4];
  float rsum[4], rss[4];
#pragma unroll
  for (int r = 0; r < 4; ++r) { rsum[r] = 0.f; rss[r] = 0.f; }
#pragma unroll
  for (int ct = 0; ct < 4; ++ct)
#pragma unroll
    for (int r = 0; r < 4; ++r) {
      float v = acc[ct][r] + bias[ct * 16 + l16];
      vv[ct][r] = v;
      rsum[r] += v;
      rss[r] += v * v;
    }
#pragma unroll
  for (int m = 1; m < 16; m <<= 1)
#pragma unroll
    for (int r = 0; r < 4; ++r) {
      rsum[r] += __shfl_xor(rsum[r], m);
      rss[r]  += __shfl_xor(rss[r], m);
    }
  float mean[4], rsl[4];
#pragma unroll
  for (int r = 0; r < 4; ++r) {
    mean[r] = rsum[r] * (1.f/64.f);
    float var = rss[r] * (1.f/64.f) - mean[r] * mean[r];
    rsl[r] = rsqrtf(var + LN_EPS);
  }
#pragma unroll
  for (int ct = 0; ct < 4; ++ct)
#pragma unroll
    for (int r = 0; r < 4; ++r) {
      int row = bm + wv * 16 + quad * 4 + r;
      int col = ct * 16 + l16;
      xsn[(size_t)row * 64 + col] = (vv[ct][r] - mean[r]) * rsl[r] * sg[col] + sb[col];
    }
}

// ---------------------------------------------------------------------------
// Tiled fp32 GEMM: C[M,N] = A[M,K] @ B[K,N] (+bias)(+add)
// ---------------------------------------------------------------------------
__global__ __launch_bounds__(256) void k_gemm(
    const float* __restrict__ A, const float* __restrict__ Bw,
    const float* __restrict__ bias, const float* __restrict__ add,
    float* __restrict__ Cout, int M, int N, int K) {
  __shared__ float sA[16][68];
  __shared__ float sB[16][64];
  int bm = blockIdx.x * 64, bn = blockIdx.y * 64;
  int tid = threadIdx.x;
  int tx = tid & 15, ty = tid >> 4;
  float acc[4][4] = {{0.f}};
  for (int k0 = 0; k0 < K; k0 += 16) {
    int e = tid << 2;
    int am = e >> 4, ak = e & 15;
    float4 a4 = *(const float4*)(A + (size_t)(bm + am) * K + k0 + ak);
    sA[ak + 0][am] = a4.x; sA[ak + 1][am] = a4.y; sA[ak + 2][am] = a4.z; sA[ak + 3][am] = a4.w;
    int bk = e >> 6, nn = e & 63;
    float4 b4 = *(const float4*)(Bw + (size_t)(k0 + bk) * N + bn + nn);
    *(float4*)&sB[bk][nn] = b4;
    __syncthreads();
#pragma unroll
    for (int kk = 0; kk < 16; ++kk) {
      float a[4], bb[4];
#pragma unroll
      for (int i = 0; i < 4; ++i) a[i] = sA[kk][ty * 4 + i];
#pragma unroll
      for (int i = 0; i < 4; ++i) bb[i] = sB[kk][tx * 4 + i];
#pragma unroll
      for (int i = 0; i < 4; ++i)
#pragma unroll
        for (int jj = 0; jj < 4; ++jj) acc[i][jj] += a[i] * bb[jj];
    }
    __syncthreads();
  }
#pragma unroll
  for (int i = 0; i < 4; ++i) {
    int row = bm + ty * 4 + i;
#pragma unroll
    for (int jj = 0; jj < 4; ++jj) {
      int col = bn + tx * 4 + jj;
      float v = acc[i][jj];
      if (bias) v += bias[col];
      if (add) v += add[(size_t)row * N + col];
      Cout[(size_t)row * N + col] = v;
    }
  }
}

// ---------------------------------------------------------------------------
// K-X2: fused  out = xd@fc_w + fc_b + (ob@proj_w + proj_b).
// ---------------------------------------------------------------------------
__global__ __launch_bounds__(256) void k_x2(
    const float* __restrict__ ob, const float* __restrict__ pw, const float* __restrict__ pb,
    const float* __restrict__ xd, const float* __restrict__ fw, const float* __restrict__ fb,
    float* __restrict__ out) {
  __shared__ float sA[16][68];
  __shared__ float sB[16][64];
  int bm = blockIdx.x * 64, bn = blockIdx.y * 64;
  int tid = threadIdx.x;
  int tx = tid & 15, ty = tid >> 4;
  int e = tid << 2;
  int am = e >> 4, ak = e & 15;
  int bk = e >> 6, nn = e & 63;
  float accP[4][4] = {{0.f}};
  // phase 1: ob @ proj_w, K = 128
  for (int k0 = 0; k0 < 128; k0 += 16) {
    float4 a4 = *(const float4*)(ob + (size_t)(bm + am) * 128 + k0 + ak);
    sA[ak + 0][am] = a4.x; sA[ak + 1][am] = a4.y; sA[ak + 2][am] = a4.z; sA[ak + 3][am] = a4.w;
    float4 b4 = *(const float4*)(pw + (size_t)(k0 + bk) * 128 + bn + nn);
    *(float4*)&sB[bk][nn] = b4;
    __syncthreads();
#pragma unroll
    for (int kk = 0; kk < 16; ++kk) {
      float a[4], bb[4];
#pragma unroll
      for (int i = 0; i < 4; ++i) a[i] = sA[kk][ty * 4 + i];
#pragma unroll
      for (int i = 0; i < 4; ++i) bb[i] = sB[kk][tx * 4 + i];
#pragma unroll
      for (int i = 0; i < 4; ++i)
#pragma unroll
        for (int jj = 0; jj < 4; ++jj) accP[i][jj] += a[i] * bb[jj];
    }
    __syncthreads();
  }
  float accF[4][4] = {{0.f}};
  // phase 2: xd @ fc_w, K = 64
  for (int k0 = 0; k0 < 64; k0 += 16) {
    float4 a4 = *(const float4*)(xd + (size_t)(bm + am) * 64 + k0 + ak);
    sA[ak + 0][am] = a4.x; sA[ak + 1][am] = a4.y; sA[ak + 2][am] = a4.z; sA[ak + 3][am] = a4.w;
    float4 b4 = *(const float4*)(fw + (size_t)(k0 + bk) * 128 + bn + nn);
    *(float4*)&sB[bk][nn] = b4;
    __syncthreads();
#pragma unroll
    for (int kk = 0; kk < 16; ++kk) {
      float a[4], bb[4];
#pragma unroll
      for (int i = 0; i < 4; ++i) a[i] = sA[kk][ty * 4 + i];
#pragma unroll
      for (int i = 0; i < 4; ++i) bb[i] = sB[kk][tx * 4 + i];
#pragma unroll
      for (int i = 0; i < 4; ++i)
#pragma unroll
        for (int jj = 0; jj < 4; ++jj) accF[i][jj] += a[i] * bb[jj];
    }
    __syncthreads();
  }
#pragma unroll
  for (int i = 0; i < 4; ++i) {
    int row = bm + ty * 4 + i;
#pragma unroll
    for (int jj = 0; jj < 4; ++jj) {
      int col = bn + tx * 4 + jj;
      out[(size_t)row * 128 + col] = accF[i][jj] + fb[col] + (accP[i][jj] + pb[col]);
    }
  }
}

// ---------------------------------------------------------------------------
// K-MLP (ROUND-17): same structure as r16, but __launch_bounds__(512, 2)
// gives the allocator a 256-VGPR budget -- r16's VGPR_Count=64 (vs ~110
// live values) means the compiler SPILLED to scratch chasing 8 waves/EU
// (FETCH rose 14.4->18.9MB = spill traffic). Grid is the occupancy limiter
// anyway (417 blocks ~ 13 waves/CU), so trading theoretical occupancy for
// zero spills is free.
// ---------------------------------------------------------------------------
__global__ __launch_bounds__(512, 2) void k_mlp(
    const float* __restrict__ A, const float* __restrict__ gg, const float* __restrict__ gb,
    const unsigned short* __restrict__ W1q, const float* __restrict__ b1,
    const unsigned short* __restrict__ W2q, const float* __restrict__ b2,
    float* __restrict__ out) {
  __shared__ __align__(16) unsigned short sW1[8192];
  __shared__ __align__(16) unsigned short sW2[8192];
  __shared__ __align__(16) unsigned short sH[8][16 * 64];
  int bm = blockIdx.x * 128;
  int tid = threadIdx.x;
  int wv = tid >> 6, lane = tid & 63, quad = lane >> 4, l16 = lane & 15;

  const short8* g1 = (const short8*)W1q;
  const short8* g2 = (const short8*)W2q;
  short8* d1 = (short8*)sW1;
  short8* d2 = (short8*)sW2;

  // weight chunk 0 prefetch (2 short8 per thread at 512 threads)
  short8 r1[2], r2[2];
#pragma unroll
  for (int i = 0; i < 2; ++i) {
    r1[i] = g1[i * 512 + tid];
    r2[i] = g2[i * 512 + tid];
  }

  // ---- load A row (wave-private strip, clamped), fused LN128 ----
  int row = bm + wv * 16 + l16;
  int rowc = row < NROW ? row : NROW - 1;
  const float* arow = A + (size_t)rowc * 128 + quad * 8;
  float av[4][8];
  float s = 0.f, ss = 0.f;
#pragma unroll
  for (int kc = 0; kc < 4; ++kc) {
    float4 a = *(const float4*)(arow + kc * 32);
    float4 c = *(const float4*)(arow + kc * 32 + 4);
    av[kc][0]=a.x; av[kc][1]=a.y; av[kc][2]=a.z; av[kc][3]=a.w;
    av[kc][4]=c.x; av[kc][5]=c.y; av[kc][6]=c.z; av[kc][7]=c.w;
    s += a.x+a.y+a.z+a.w + c.x+c.y+c.z+c.w;
    ss += a.x*a.x+a.y*a.y+a.z*a.z+a.w*a.w + c.x*c.x+c.y*c.y+c.z*c.z+c.w*c.w;
  }
  s += __shfl_xor(s, 16);  ss += __shfl_xor(ss, 16);
  s += __shfl_xor(s, 32);  ss += __shfl_xor(ss, 32);
  float m = s * (1.f/128.f);
  float var = ss * (1.f/128.f) - m * m;
  float rs = rsqrtf(var + LN_EPS);
  short8 af[4];
#pragma unroll
  for (int kc = 0; kc < 4; ++kc) {
    int c0 = kc * 32 + quad * 8;
    float4 ga = *(const float4*)(gg + c0);
    float4 gc = *(const float4*)(gg + c0 + 4);
    float4 ba = *(const float4*)(gb + c0);
    float4 bc = *(const float4*)(gb + c0 + 4);
    af[kc][0] = (short)f2bf((av[kc][0]-m)*rs*ga.x + ba.x);
    af[kc][1] = (short)f2bf((av[kc][1]-m)*rs*ga.y + ba.y);
    af[kc][2] = (short)f2bf((av[kc][2]-m)*rs*ga.z + ba.z);
    af[kc][3] = (short)f2bf((av[kc][3]-m)*rs*ga.w + ba.w);
    af[kc][4] = (short)f2bf((av[kc][4]-m)*rs*gc.x + bc.x);
    af[kc][5] = (short)f2bf((av[kc][5]-m)*rs*gc.y + bc.y);
    af[kc][6] = (short)f2bf((av[kc][6]-m)*rs*gc.z + bc.z);
    af[kc][7] = (short)f2bf((av[kc][7]-m)*rs*gc.w + bc.w);
  }

  f32x4 oacc[8];
#pragma unroll
  for (int ct = 0; ct < 8; ++ct) oacc[ct] = (f32x4){0.f, 0.f, 0.f, 0.f};

  for (int hh = 0; hh < 8; ++hh) {
#pragma unroll
    for (int i = 0; i < 2; ++i) {
      d1[i * 512 + tid] = r1[i];
      d2[i * 512 + tid] = r2[i];
    }
    __syncthreads();   // chunk visible to all waves
    if (hh < 7) {
      int base = (hh + 1) * 1024;
#pragma unroll
      for (int i = 0; i < 2; ++i) {
        r1[i] = g1[base + i * 512 + tid];
        r2[i] = g2[base + i * 512 + tid];
      }
    }
    // GEMM1: H-chunk[16 x 64], A from registers
    f32x4 acc1[4];
#pragma unroll
    for (int ct = 0; ct < 4; ++ct) acc1[ct] = (f32x4){0.f, 0.f, 0.f, 0.f};
#pragma unroll
    for (int kc = 0; kc < 4; ++kc) {
      int sidx = kc * 4 + quad;
#pragma unroll
      for (int ct = 0; ct < 4; ++ct) {
        short8 bf = *(const short8*)&sW1[(sidx * 64 + ct * 16 + l16) << 3];
        acc1[ct] = __builtin_amdgcn_mfma_f32_16x16x32_bf16(af[kc], bf, acc1[ct], 0, 0, 0);
      }
    }
    // bias + GELU -> per-wave H tile (bf16, swizzled; wave-private)
#pragma unroll
    for (int ct = 0; ct < 4; ++ct)
#pragma unroll
      for (int r = 0; r < 4; ++r) {
        float v = acc1[ct][r] + b1[hh * 64 + ct * 16 + l16];
        v = gelu_fast(v);
        int rit = quad * 4 + r;
        int col = ct * 16 + l16;
        int ck = (col >> 3) ^ (rit & 7);
        sH[wv][rit * 64 + ((ck & 7) << 3) + (col & 7)] = f2bf(v);
      }
    // GEMM2: O += H-chunk @ W2[hh*64..+64, :]
#pragma unroll
    for (int kg = 0; kg < 2; ++kg) {
      int ckh = kg * 4 + quad;
      short8 hf = *(const short8*)&sH[wv][l16 * 64 + (((ckh ^ (l16 & 7)) & 7) << 3)];
      int sidx = kg * 4 + quad;
#pragma unroll
      for (int ct = 0; ct < 8; ++ct) {
        short8 bf = *(const short8*)&sW2[(sidx * 128 + ct * 16 + l16) << 3];
        oacc[ct] = __builtin_amdgcn_mfma_f32_16x16x32_bf16(hf, bf, oacc[ct], 0, 0, 0);
      }
    }
    __syncthreads();   // all waves done reading sW1/sW2 before overwrite
  }
#pragma unroll
  for (int ct = 0; ct < 8; ++ct)
#pragma unroll
    for (int r = 0; r < 4; ++r) {
      int orow = bm + wv * 16 + quad * 4 + r;
      int col = ct * 16 + l16;
      if (orow < NROW)
        out[(size_t)orow * 128 + col] += oacc[ct][r] + b2[col];
    }
}

// ---------------------------------------------------------------------------
// K7 (ROUND-17): MFMA attention with V stored TRANSPOSED in LDS.
// Old PV phase built each B-frag from 8 scalar ds_read_u16 (224 scalar LDS
// reads per wave -- the classic ds_read_u16 antipattern). New: ldsVT[dcol]
// [key], row stride 232 halves (464B, 16B-aligned, 2-way bank conflict =
// free) -> each B-frag is ONE ds_read_b128 over contiguous keys (28 reads).
// Staging pays 8 scalar ds_write_u16/thread once.
// ---------------------------------------------------------------------------
__global__ __launch_bounds__(256) void k_attn(const float* __restrict__ q,
    const float* __restrict__ kg, const float* __restrict__ vg, float* __restrict__ o) {
  __shared__ __align__(16) unsigned short ldsKP[14848];
  __shared__ __align__(16) unsigned short ldsVT[64 * 232];   // 29,696 B
  int blk = blockIdx.x;
  int chunk = blk % 14;
  int bh = blk / 14;
  int h = bh & 1, b = bh >> 1;
  int tid = threadIdx.x;
  int wv = tid >> 6, lane = tid & 63;
  int quad = lane >> 4, l16 = lane & 15;

  const float* kb = kg + (size_t)b * NS * 128 + h * 64;
  const float* vb = vg + (size_t)b * NS * 128 + h * 64;

  for (int t = tid; t < KPAD * 8; t += 256) {
    int key = t >> 3, ck = t & 7;
    short8 pk;
    float pv[8];
    if (key < NS) {
      const float* ksrc = kb + (size_t)key * 128 + ck * 8;
      const float* vsrc = vb + (size_t)key * 128 + ck * 8;
      float4 a = *(const float4*)ksrc;
      float4 c = *(const float4*)(ksrc + 4);
      pk[0]=(short)f2bf(a.x); pk[1]=(short)f2bf(a.y); pk[2]=(short)f2bf(a.z); pk[3]=(short)f2bf(a.w);
      pk[4]=(short)f2bf(c.x); pk[5]=(short)f2bf(c.y); pk[6]=(short)f2bf(c.z); pk[7]=(short)f2bf(c.w);
      float4 e = *(const float4*)vsrc;
      float4 g = *(const float4*)(vsrc + 4);
      pv[0]=e.x; pv[1]=e.y; pv[2]=e.z; pv[3]=e.w;
      pv[4]=g.x; pv[5]=g.y; pv[6]=g.z; pv[7]=g.w;
    } else {
      pk = (short8)0;
#pragma unroll
      for (int j = 0; j < 8; ++j) pv[j] = 0.f;
    }
    *(short8*)&ldsKP[key * 64 + ((ck ^ (key & 7)) << 3)] = pk;
#pragma unroll
    for (int j = 0; j < 8; ++j)
      ldsVT[(ck * 8 + j) * 232 + key] = f2bf(pv[j]);
  }

  int qrow = chunk * 64 + wv * 16 + l16;
  int qrowc = qrow < ND ? qrow : ND - 1;
  const float* qsrc = q + ((size_t)b * ND + qrowc) * 128 + h * 64 + quad * 8;
  short8 aq0, aq1;
  {
    float4 a = *(const float4*)qsrc;
    float4 c = *(const float4*)(qsrc + 4);
    aq0[0]=(short)f2bf(a.x); aq0[1]=(short)f2bf(a.y); aq0[2]=(short)f2bf(a.z); aq0[3]=(short)f2bf(a.w);
    aq0[4]=(short)f2bf(c.x); aq0[5]=(short)f2bf(c.y); aq0[6]=(short)f2bf(c.z); aq0[7]=(short)f2bf(c.w);
    float4 e = *(const float4*)(qsrc + 32);
    float4 g = *(const float4*)(qsrc + 36);
    aq1[0]=(short)f2bf(e.x); aq1[1]=(short)f2bf(e.y); aq1[2]=(short)f2bf(e.z); aq1[3]=(short)f2bf(e.w);
    aq1[4]=(short)f2bf(g.x); aq1[5]=(short)f2bf(g.y); aq1[6]=(short)f2bf(g.z); aq1[7]=(short)f2bf(g.w);
  }
  __syncthreads();

  f32x4 acc[14];
#pragma unroll
  for (int ct = 0; ct < 14; ++ct) {
    int key = ct * 16 + l16;
    short8 bk0 = *(const short8*)&ldsKP[key * 64 + ((quad ^ (key & 7)) << 3)];
    short8 bk1 = *(const short8*)&ldsKP[key * 64 + (((4 + quad) ^ (key & 7)) << 3)];
    f32x4 z = {0.f, 0.f, 0.f, 0.f};
    z = __builtin_amdgcn_mfma_f32_16x16x32_bf16(aq0, bk0, z, 0, 0, 0);
    z = __builtin_amdgcn_mfma_f32_16x16x32_bf16(aq1, bk1, z, 0, 0, 0);
    acc[ct] = z;
  }

  const float scale = 0.17677669529663687f;  // 32^-0.5
  float rmax[4] = {-1e30f, -1e30f, -1e30f, -1e30f};
#pragma unroll
  for (int ct = 0; ct < 14; ++ct) {
    bool msk = (ct * 16 + l16) >= NS;
#pragma unroll
    for (int r = 0; r < 4; ++r) {
      float sv = msk ? -1e30f : acc[ct][r] * scale;
      acc[ct][r] = sv;
      rmax[r] = fmaxf(rmax[r], sv);
    }
  }
#pragma unroll
  for (int m = 1; m < 16; m <<= 1)
#pragma unroll
    for (int r = 0; r < 4; ++r) rmax[r] = fmaxf(rmax[r], __shfl_xor(rmax[r], m));
  float rsum[4] = {0.f, 0.f, 0.f, 0.f};
#pragma unroll
  for (int ct = 0; ct < 14; ++ct)
#pragma unroll
    for (int r = 0; r < 4; ++r) {
      float e = __expf(acc[ct][r] - rmax[r]);
      acc[ct][r] = e;
      rsum[r] += e;
    }
#pragma unroll
  for (int m = 1; m < 16; m <<= 1)
#pragma unroll
    for (int r = 0; r < 4; ++r) rsum[r] += __shfl_xor(rsum[r], m);
  float rinv[4];
#pragma unroll
  for (int r = 0; r < 4; ++r) rinv[r] = 1.f / rsum[r];

  __syncthreads();

#pragma unroll
  for (int ct = 0; ct < 14; ++ct)
#pragma unroll
    for (int r = 0; r < 4; ++r) {
      int prow = wv * 16 + quad * 4 + r;
      ldsKP[prow * 232 + ct * 16 + l16] = f2bf(acc[ct][r] * rinv[r]);
    }
  __syncthreads();

  f32x4 oacc[4];
#pragma unroll
  for (int ot = 0; ot < 4; ++ot) oacc[ot] = (f32x4){0.f, 0.f, 0.f, 0.f};
#pragma unroll
  for (int kc = 0; kc < 7; ++kc) {
    short8 ap = *(const short8*)&ldsKP[(wv * 16 + l16) * 232 + kc * 32 + quad * 8];
    int keybase = kc * 32 + quad * 8;
#pragma unroll
    for (int ot = 0; ot < 4; ++ot) {
      int dcol = ot * 16 + l16;
      short8 bv = *(const short8*)&ldsVT[dcol * 232 + keybase];
      oacc[ot] = __builtin_amdgcn_mfma_f32_16x16x32_bf16(ap, bv, oacc[ot], 0, 0, 0);
    }
  }

#pragma unroll
  for (int ot = 0; ot < 4; ++ot)
#pragma unroll
    for (int r = 0; r < 4; ++r) {
      int rowg = chunk * 64 + wv * 16 + quad * 4 + r;
      if (rowg < ND)
        o[((size_t)b * ND + rowg) * 128 + h * 64 + ot * 16 + l16] = oacc[ot][r];
    }
}

// ---------------------------------------------------------------------------
// K8: bilinear grid-sample of pos_embed at pos_down, accumulate into out
// ---------------------------------------------------------------------------
__global__ __launch_bounds__(256) void k_posfeat(const float* __restrict__ pd,
    const float* __restrict__ pe, float* __restrict__ out) {
  int t = blockIdx.x * 256 + threadIdx.x;
  int row = t >> 5, lane = t & 31;
  if (row >= B_ * ND) return;
  float gx = pd[(size_t)2*row] * 2.f - 1.f;
  float gy = pd[(size_t)2*row+1] * 2.f - 1.f;
  float ix = ((gx + 1.f) * 56.f - 1.f) * 0.5f;
  float iy = ((gy + 1.f) * 56.f - 1.f) * 0.5f;
  float x0 = floorf(ix), y0 = floorf(iy);
  float wx1 = ix - x0, wy1 = iy - y0;
  float wx0 = 1.f - wx1, wy0 = 1.f - wy1;
  float4 acc = make_float4(0.f, 0.f, 0.f, 0.f);
#pragma unroll
  for (int cy = 0; cy < 2; ++cy) {
#pragma unroll
    for (int cx = 0; cx < 2; ++cx) {
      float xc = x0 + (float)cx, yc = y0 + (float)cy;
      float wgt = (cx ? wx1 : wx0) * (cy ? wy1 : wy0);
      bool valid = (xc >= 0.f) && (xc < 56.f) && (yc >= 0.f) && (yc < 56.f);
      if (valid) {
        int lin = (int)yc * 56 + (int)xc;
        float4 pv = ((const float4*)(pe + (size_t)lin * 128))[lane];
        acc.x += wgt * pv.x; acc.y += wgt * pv.y;
        acc.z += wgt * pv.z; acc.w += wgt * pv.w;
      }
    }
  }
  float4* op = (float4*)(out + (size_t)row * 128) + lane;
  float4 cur = *op;
  cur.x += acc.x; cur.y += acc.y; cur.z += acc.z; cur.w += acc.w;
  *op = cur;
}

// ---------------------------------------------------------------------------
// launcher
// ---------------------------------------------------------------------------
extern "C" void kernel_launch(void* const* d_in, const int* in_sizes, int n_in,
                              void* d_out, int out_size, void* d_ws, size_t ws_size,
                              hipStream_t stream) {
  const float* x      = (const float*)d_in[0];
  const float* pos    = (const float*)d_in[1];
  const float* pe     = (const float*)d_in[2];
  const float* nu     = (const float*)d_in[3];
  const float* norm_g = (const float*)d_in[4];
  const float* norm_b = (const float*)d_in[5];
  const float* conf_w = (const float*)d_in[6];
  const float* conf_b = (const float*)d_in[7];
  const float* n1g    = (const float*)d_in[8];
  const float* n1b    = (const float*)d_in[9];
  const float* q_w    = (const float*)d_in[10];
  const float* k_w    = (const float*)d_in[11];
  const float* v_w    = (const float*)d_in[12];
  const float* proj_w = (const float*)d_in[13];
  const float* proj_b = (const float*)d_in[14];
  const float* sr_w   = (const float*)d_in[15];
  const float* sr_b   = (const float*)d_in[16];
  const float* srn_g  = (const float*)d_in[17];
  const float* srn_b  = (const float*)d_in[18];
  const float* fc_w   = (const float*)d_in[19];
  const float* fc_b   = (const float*)d_in[20];
  const float* n2g    = (const float*)d_in[21];
  const float* n2b    = (const float*)d_in[22];
  const float* fc1_w  = (const float*)d_in[23];
  const float* fc1_b  = (const float*)d_in[24];
  const float* fc2_w  = (const float*)d_in[25];
  const float* fc2_b  = (const float*)d_in[26];

  char* ws = (char*)d_ws;
  // workspace layout (bytes); total 190,578,688 (unchanged)
  double*         scores = (double*)(ws + 0);                //  1,580,544
  int*            idx    = (int*)(ws + 1605632);             //    200,704
  float*          xd     = (float*)(ws + 1835008);           // 13,647,872
  float*          xn     = (float*)(ws + 15728640);          // 13,647,872
  float*          pd     = (float*)(ws + 29491200);          //    426,496
  float*          qb     = (float*)(ws + 30408704);          // 27,295,744; T alias; later q
  float*          ob     = (float*)(ws + 58720256);          // 27,295,744; T tail alias
  unsigned short* Wcp    = (unsigned short*)(ws + 86507520); //    131,072 (conv weights, bf16 packed)
  unsigned short* W1p    = (unsigned short*)(ws + 86769664); //    131,072
  unsigned short* W2p    = (unsigned short*)(ws + 86900736); //    131,072 (ends 87,031,808)
  char*           big    = ws + 87031808;                    // 103,546,880 region
  float*          S      = (float*)big;                      // 52,183,040 (dead after transpose)
  float*          T      = qb;                               // 51,380,224 channel planes (dead after filter2)
  float*          Kc     = (float*)(big + 52183040);         //  7,225,344 coefficient planes (dead after filter2)
  float*          P      = (float*)big;                      // 51,380,224 (reuses dead S; dead after conv)
  float*          xs_n   = (float*)(big + 62619648);         //  3,211,264
  float*          kbuf   = (float*)(big + 65830912);         //  6,422,528
  float*          vbuf   = (float*)(big + 72253440);         //  6,422,528 (ends 78,675,968)
  float*          Mbuf   = (float*)(big + 78675968);         //    802,816 mask plane (dead after coef)
  int*            head   = (int*)(big + 79478784);           //    802,816 (dead after accum)
  int*            nxt    = (int*)(big + 80281600);           //    802,816 (ends 81,084,416)
  float*          out    = (float*)d_out;

  // 1) f64 conf+gumbel scores
  k_conf<<<(B_ * N_) / 256, 256, 0, stream>>>(x, norm_g, norm_b, conf_w, conf_b, nu, scores);
  // 2) top-784 per batch: exact counting-sort rank (one block per batch)
  k_topk2<<<B_, 256, 0, stream>>>(scores, idx);
  // 3) gather + LN(norm1)
  k_gather_ln<<<(B_ * ND + 255) / 256, 256, 0, stream>>>(x, pos, idx, n1g, n1b, xd, xn, pd);
  // 4) token2map: per-pixel linked lists then gather-accumulate
  hipMemsetAsync(head, 0xFF, (size_t)B_ * HW * sizeof(int), stream);
  k_link<<<(B_ * N_ + 255) / 256, 256, 0, stream>>>(pos, head, nxt);
  k_accum<<<(B_ * HW * 64) / 256, 256, 0, stream>>>(x, n1g, n1b, head, nxt, S);
  // 5) gaussian reconstruct: transpose (+mask plane), coef, 3x3 conv
  k_transpose<<<BHW / 64, 256, 0, stream>>>(S, T, Mbuf);
  k_coef<<<BHW / 256, 256, 0, stream>>>(Mbuf, Kc);
  k_filter2<<<B_ * 64, 256, 0, stream>>>(T, Kc, P);
  // 6) weight packing (conv + MLP); MFMA conv-as-GEMM with fused LN64
  k_wtp<<<65536 / 256, 256, 0, stream>>>(sr_w, Wcp);
  k_wpack<<<65536 / 256, 256, 0, stream>>>(fc1_w, fc2_w, W1p, W2p);
  k_conv<<<B_ * NS / 64, 256, 0, stream>>>(P, Wcp, sr_b, srn_g, srn_b, xs_n);
  // 7) k, v, q projections (q GEMM overwrites T region -- T is dead by now)
  dim3 g_kv(B_ * NS / 64, 2);
  k_gemm<<<g_kv, 256, 0, stream>>>(xs_n, k_w, nullptr, nullptr, kbuf, B_ * NS, 128, 64);
  k_gemm<<<g_kv, 256, 0, stream>>>(xs_n, v_w, nullptr, nullptr, vbuf, B_ * NS, 128, 64);
  dim3 g_row(B_ * ND / 64, 2);
  k_gemm<<<g_row, 256, 0, stream>>>(xn, q_w, nullptr, nullptr, qb, B_ * ND, 128, 64);
  // 8) attention (MFMA bf16, V^T LDS layout)
  k_attn<<<B_ * 2 * 14, 256, 0, stream>>>(qb, kbuf, vbuf, ob);
  // 9) fused x2 = xd@fc_w + fc_b + (ob@proj_w + proj_b) -> d_out
  k_x2<<<g_row, 256, 0, stream>>>(ob, proj_w, proj_b, xd, fc_w, fc_b, out);
  // 10) MLP: fused LN128 + fc1 + gelu + fc2 (128-row 8-wave blocks)
  k_mlp<<<(NROW + 127) / 128, 512, 0, stream>>>(out, n2g, n2b, W1p, fc1_b, W2p, fc2_b, out);
  // 11) + pos_feat (bilinear grid sample)
  k_posfeat<<<(B_ * ND * 32) / 256, 256, 0, stream>>>(pd, pe, out);
}

// Round 13
// 528.818 us; speedup vs baseline: 1.0392x; 1.0392x over previous
//
#include <hip/hip_runtime.h>
#include <math.h>

#define DEVINL __device__ __forceinline__

constexpr int B_ = 64;
constexpr int N_ = 3136;
constexpr int C_ = 64;        // DIM
constexpr int NG = 49;        // N_grid
constexpr int NSAMP = 784;    // SAMPLE_NUM
constexpr int ND = NG + NSAMP;     // 833
constexpr int NREST = N_ - NG;     // 3087
constexpr int H_ = 56, W_ = 56;
constexpr int HW = H_ * W_;        // 3136
constexpr int BHW = B_ * HW;       // 200704
constexpr int NS = 14 * 14;        // 196 kv tokens
constexpr int KPAD = 224;          // 196 padded to 7*32
constexpr int NROW = B_ * ND;      // 53312 = 833 * 64 exactly
constexpr float LN_EPS = 1e-5f;
constexpr float EPS6 = 1e-6f;

typedef __attribute__((ext_vector_type(8))) short short8;
typedef __attribute__((ext_vector_type(4))) float f32x4;

DEVINL unsigned short f2bf(float f) {
  unsigned int u = __float_as_uint(f);
  unsigned int r = u + 0x7FFFu + ((u >> 16) & 1u);
  return (unsigned short)(r >> 16);
}

// Fast exact-GELU: erf via Abramowitz-Stegun 7.1.26 (|err| <= 1.5e-7).
DEVINL float gelu_fast(float v) {
  float x = v * 0.70710678118654752f;
  float ax = fabsf(x);
  float t = 1.f / fmaf(0.3275911f, ax, 1.f);
  float poly = t * fmaf(t, fmaf(t, fmaf(t, fmaf(t, 1.061405429f, -1.453152027f),
                        1.421413741f), -0.284496736f), 0.254829592f);
  float e = 1.f - poly * __expf(-x * x);
  float erfv = copysignf(e, x);
  return 0.5f * v * (1.f + erfv);
}

// ---------------------------------------------------------------------------
// K1: conf scores in FP64 (discrete top-k decision must match f64 np ref)
// ---------------------------------------------------------------------------
__global__ __launch_bounds__(256) void k_conf(
    const float* __restrict__ x, const float* __restrict__ ng, const float* __restrict__ nb,
    const float* __restrict__ cw, const float* __restrict__ cb,
    const float* __restrict__ nu, double* __restrict__ scores) {
  int t = blockIdx.x * 256 + threadIdx.x;
  if (t >= B_ * N_) return;
  int b = t / N_, n = t - b * N_;
  if (n < NG) return;
  const float4* row = (const float4*)(x + (size_t)t * C_);
  float v[C_];
#pragma unroll
  for (int i = 0; i < 16; ++i) {
    float4 r = row[i];
    v[4*i] = r.x; v[4*i+1] = r.y; v[4*i+2] = r.z; v[4*i+3] = r.w;
  }
  double sd = 0.0;
#pragma unroll
  for (int i = 0; i < C_; ++i) sd += (double)v[i];
  double md = sd * (1.0/64.0);
  double vd = 0.0;
#pragma unroll
  for (int i = 0; i < C_; ++i) { double d = (double)v[i] - md; vd += d * d; }
  vd *= (1.0/64.0);
  double rsd = 1.0 / sqrt(vd + 1e-5);
  double conf = (double)cb[0];
#pragma unroll
  for (int i = 0; i < C_; ++i) {
    double xnv = ((double)v[i] - md) * rsd;
    conf += (xnv * (double)ng[i] + (double)nb[i]) * (double)cw[i];
  }
  double u = (double)nu[(size_t)b * NREST + (n - NG)];
  double noise = -log(-log(u + 1e-6) + 1e-6);
  scores[(size_t)b * NREST + (n - NG)] = conf + noise;
}

// ---------------------------------------------------------------------------
// K2: exact top-784 via counting-sort rank. One block per batch.
// ---------------------------------------------------------------------------
constexpr int NB = 2048;

__global__ __launch_bounds__(256) void k_topk2(const double* __restrict__ scores,
                                               int* __restrict__ idx) {
  __shared__ double sk[NREST];              // 24,696 B
  __shared__ int hist[NB];                  //  8,192 B
  __shared__ int bstart[NB];                //  8,192 B
  __shared__ int fill[NB];                  //  8,192 B
  __shared__ unsigned short order[NREST];   //  6,174 B
  __shared__ float redmin[256], redmax[256];//  2,048 B
  __shared__ int scanbuf[256];              //  1,024 B   (~58.5 KB total)
  int b = blockIdx.x, tid = threadIdx.x;
  const double* sc = scores + (size_t)b * NREST;
  float lmin = 3.4e38f, lmax = -3.4e38f;
  for (int i = tid; i < NREST; i += 256) {
    double d = sc[i];
    sk[i] = d;
    float f = (float)d;
    lmin = fminf(lmin, f); lmax = fmaxf(lmax, f);
  }
  for (int i = tid; i < NB; i += 256) hist[i] = 0;
  redmin[tid] = lmin; redmax[tid] = lmax;
  __syncthreads();
  for (int s = 128; s > 0; s >>= 1) {
    if (tid < s) {
      redmin[tid] = fminf(redmin[tid], redmin[tid + s]);
      redmax[tid] = fmaxf(redmax[tid], redmax[tid + s]);
    }
    __syncthreads();
  }
  float fmn = redmin[0];
  float scale = (float)NB / fmaxf(redmax[0] - fmn, 1e-30f);
  // histogram
  for (int i = tid; i < NREST; i += 256) {
    float f = (float)sk[i];
    int bn = (int)((f - fmn) * scale);
    bn = bn < 0 ? 0 : (bn > NB - 1 ? NB - 1 : bn);
    atomicAdd(&hist[bn], 1);
  }
  __syncthreads();
  // suffix scan: bstart[bin] = sum over strictly-higher bins.
  int base = tid * 8;          // this thread owns bins [base, base+8)
  int s_t = 0;
#pragma unroll
  for (int i = 0; i < 8; ++i) s_t += hist[base + i];
  scanbuf[tid] = s_t;
  __syncthreads();
  int val = s_t;
  for (int off = 1; off < 256; off <<= 1) {
    int other = (tid + off < 256) ? scanbuf[tid + off] : 0;
    __syncthreads();
    val += other;
    scanbuf[tid] = val;
    __syncthreads();
  }
  int run = val - s_t;         // sum over threads t' > tid
#pragma unroll
  for (int i = 7; i >= 0; --i) {
    bstart[base + i] = run;
    run += hist[base + i];
  }
  __syncthreads();
  for (int i = tid; i < NB; i += 256) fill[i] = bstart[i];
  __syncthreads();
  // scatter element ids into bin-grouped order[]
  for (int i = tid; i < NREST; i += 256) {
    float f = (float)sk[i];
    int bn = (int)((f - fmn) * scale);
    bn = bn < 0 ? 0 : (bn > NB - 1 ? NB - 1 : bn);
    int pos = atomicAdd(&fill[bn], 1);
    order[pos] = (unsigned short)i;
  }
  __syncthreads();
  // exact rank = bstart[bin] + within-bin f64 rank; write winners
  for (int i = tid; i < NREST; i += 256) {
    double ke = sk[i];
    float f = (float)ke;
    int bn = (int)((f - fmn) * scale);
    bn = bn < 0 ? 0 : (bn > NB - 1 ? NB - 1 : bn);
    int st = bstart[bn], m = hist[bn];
    int r = st;
    for (int p = st; p < st + m; ++p) {
      int j = order[p];
      double kj = sk[j];
      r += (int)((kj > ke) | ((kj == ke) & (j < i)));
    }
    if (r < NSAMP) idx[(size_t)b * NSAMP + r] = i;
  }
}

// ---------------------------------------------------------------------------
// K3: gather x_down/pos_down rows; LayerNorm(x_down, norm1) -> xn
// ---------------------------------------------------------------------------
__global__ __launch_bounds__(256) void k_gather_ln(
    const float* __restrict__ x, const float* __restrict__ pos, const int* __restrict__ idx,
    const float* __restrict__ n1g, const float* __restrict__ n1b,
    float* __restrict__ xd, float* __restrict__ xn, float* __restrict__ pd) {
  int t = blockIdx.x * 256 + threadIdx.x;
  if (t >= B_ * ND) return;
  int b = t / ND, r = t - b * ND;
  int srcn = (r < NG) ? r : (NG + idx[(size_t)b * NSAMP + (r - NG)]);
  const float4* row = (const float4*)(x + ((size_t)b * N_ + srcn) * C_);
  float4* xdr = (float4*)(xd + (size_t)t * C_);
  float v[C_];
  float s = 0.f, ss = 0.f;
#pragma unroll
  for (int i = 0; i < 16; ++i) {
    float4 rr = row[i];
    xdr[i] = rr;
    v[4*i] = rr.x; v[4*i+1] = rr.y; v[4*i+2] = rr.z; v[4*i+3] = rr.w;
    s += rr.x + rr.y + rr.z + rr.w;
    ss += rr.x*rr.x + rr.y*rr.y + rr.z*rr.z + rr.w*rr.w;
  }
  float m = s * (1.f/64.f);
  float var = ss * (1.f/64.f) - m*m;
  float rs = rsqrtf(var + LN_EPS);
#pragma unroll
  for (int i = 0; i < C_; ++i)
    xn[(size_t)t * C_ + i] = (v[i] - m) * rs * n1g[i] + n1b[i];
  pd[(size_t)2*t]   = pos[((size_t)b * N_ + srcn) * 2];
  pd[(size_t)2*t+1] = pos[((size_t)b * N_ + srcn) * 2 + 1];
}

// ---------------------------------------------------------------------------
// K4a: build per-pixel token linked lists (1 atomicExch per token).
// ---------------------------------------------------------------------------
__global__ __launch_bounds__(256) void k_link(
    const float* __restrict__ pos, int* __restrict__ head, int* __restrict__ next) {
  int tok = blockIdx.x * 256 + threadIdx.x;
  if (tok >= B_ * N_) return;
  int b = tok / N_;
  double px = fmin(fmax((double)pos[(size_t)2*tok],   0.0), 1.0) * (double)(W_ - 1);
  double py = fmin(fmax((double)pos[(size_t)2*tok+1], 0.0), 1.0) * (double)(H_ - 1);
  int xi = (int)rint(px), yi = (int)rint(py);
  int p = b * HW + yi * W_ + xi;
  next[tok] = atomicExch(&head[p], tok);
}

// ---------------------------------------------------------------------------
// K4b: gather-accumulate. One WAVE per pixel, lane = channel.
// ---------------------------------------------------------------------------
__global__ __launch_bounds__(256) void k_accum(
    const float* __restrict__ x, const float* __restrict__ n1g, const float* __restrict__ n1b,
    const int* __restrict__ head, const int* __restrict__ next, float* __restrict__ S) {
  int gt = blockIdx.x * 256 + threadIdx.x;
  int p = gt >> 6, lane = gt & 63;
  if (p >= B_ * HW) return;
  float g = n1g[lane], bb = n1b[lane];
  float acc = 0.f, cnt = 0.f;
  int tok = head[p];
  while (tok >= 0) {
    float v = x[(size_t)tok * C_ + lane];
    float s = v, ss = v * v;
#pragma unroll
    for (int m = 32; m > 0; m >>= 1) {
      s += __shfl_xor(s, m);
      ss += __shfl_xor(ss, m);
    }
    float mean = s * (1.f/64.f);
    float var = ss * (1.f/64.f) - mean * mean;
    float rs = rsqrtf(var + LN_EPS);
    acc += (v - mean) * rs * g + bb;
    cnt += 1.f;
    tok = next[tok];
  }
  float* base = S + (size_t)p * 65;
  base[lane] = acc;
  if (lane == 0) base[64] = cnt;
}

// ---------------------------------------------------------------------------
// K5b: transpose S[p][65] -> channel planes T[b][c][HW] + mask plane M.
// ---------------------------------------------------------------------------
__global__ __launch_bounds__(256) void k_transpose(const float* __restrict__ S,
                                                   float* __restrict__ T,
                                                   float* __restrict__ M) {
  __shared__ float ls[64 * 65];
  int g0 = blockIdx.x * 64;            // global pixel base (batch-major)
  int b = g0 / HW, p0 = g0 - b * HW;
  const float4* src = (const float4*)(S + (size_t)g0 * 65);
  for (int i = threadIdx.x; i < (64 * 65) / 4; i += 256)
    *(float4*)&ls[i * 4] = src[i];
  __syncthreads();
  for (int i = threadIdx.x; i < 64 * 64; i += 256) {
    int c = i >> 6, px = i & 63;
    T[((size_t)(b * 64 + c)) * HW + p0 + px] = ls[px * 65 + c];
  }
  for (int i = threadIdx.x; i < 64; i += 256)
    M[(size_t)g0 + i] = ls[i * 65 + 64];
}

// ---------------------------------------------------------------------------
// K5a: per-pixel 3x3 coefficient planes, mask read from contiguous M plane.
// ---------------------------------------------------------------------------
__global__ __launch_bounds__(256) void k_coef(const float* __restrict__ M, float* __restrict__ Kc) {
  int t = blockIdx.x * 256 + threadIdx.x;
  if (t >= BHW) return;
  int b = t / HW, p = t - b * HW;
  int y = p / W_, x = p - y * W_;
  const float* Mb = M + (size_t)b * HW;
  const float e1 = 0.882496902584595f;   // exp(-1/8)
  const float e2 = 0.778800783071405f;   // exp(-1/4)
  const float Z = 1.f + 4.f * (e1 + e2);
  float m0 = Mb[p];
  float mb0 = m0 > 0.f ? 1.f : 0.f;
  float cfac = mb0 / (m0 + EPS6);
  float sc[9];
  float mi = 0.f;
  int q = 0;
#pragma unroll
  for (int dy = -1; dy <= 1; ++dy) {
#pragma unroll
    for (int dx = -1; dx <= 1; ++dx) {
      int ny = y + dy, nx = x + dx;
      bool in = (ny >= 0 && ny < H_ && nx >= 0 && nx < W_);
      float w = ((dx == 0 && dy == 0) ? 1.f : ((dx*dx + dy*dy) == 1 ? e1 : e2)) / Z;
      float mm = in ? Mb[ny * W_ + nx] : 0.f;
      float mb = mm > 0.f ? 1.f : 0.f;
      mi += w * mb;
      sc[q] = in ? (w * mb / (mm + EPS6)) : 0.f;
      ++q;
    }
  }
  float outer = (1.f - mb0) * ((mi > 0.f ? 1.f : 0.f) / (mi + EPS6));
#pragma unroll
  for (int qq = 0; qq < 9; ++qq) {
    float cq = outer * sc[qq];
    if (qq == 4) cq += cfac;
    Kc[(size_t)qq * BHW + t] = cq;
  }
}

// ---------------------------------------------------------------------------
// K5c: spatially-varying 3x3 conv on channel planes -> conv-patch layout P.
// ---------------------------------------------------------------------------
__global__ __launch_bounds__(256) void k_filter2(
    const float* __restrict__ T, const float* __restrict__ Kc, float* __restrict__ P) {
  int plane = blockIdx.x;              // b*64 + c
  int b = plane >> 6, c = plane & 63;
  int tid = threadIdx.x;
  const float* Tp = T + (size_t)plane * HW;
  const float* Kb = Kc + (size_t)b * HW;
  for (int p0 = 0; p0 < HW; p0 += 256) {
    int p = p0 + tid;
    if (p < HW) {
      int y = p / W_, x = p - y * W_;
      float acc = 0.f;
      int q = 0;
#pragma unroll
      for (int dy = -1; dy <= 1; ++dy) {
#pragma unroll
        for (int dx = -1; dx <= 1; ++dx) {
          int ny = y + dy; ny = ny < 0 ? 0 : (ny > H_ - 1 ? H_ - 1 : ny);
          int nx = x + dx; nx = nx < 0 ? 0 : (nx > W_ - 1 ? W_ - 1 : nx);
          acc += Kb[(size_t)q * BHW + p] * Tp[ny * W_ + nx];
          ++q;
        }
      }
      int j = (y >> 2) * 14 + (x >> 2);
      int colb = ((y & 3) << 2) + (x & 3);
      P[((size_t)(b * NS + j)) * 1024 + c * 16 + colb] = acc;
    }
  }
}

// ---------------------------------------------------------------------------
// K6: pack sr_w into chunk-contiguous bf16 B-frag layout for the conv GEMM.
// ---------------------------------------------------------------------------
__global__ __launch_bounds__(256) void k_wtp(const float* __restrict__ srw,
                                             unsigned short* __restrict__ Wcp) {
  int t = blockIdx.x * 256 + threadIdx.x;
  if (t >= 65536) return;
  int j = t & 7;
  int n = (t >> 3) & 63;        // co
  int s = (t >> 9) & 15;        // kc*4 + quad
  int ch = t >> 13;             // 0..7
  int k = ch * 128 + (s >> 2) * 32 + (s & 3) * 8 + j;
  int ci = k >> 4, r = k & 15;
  Wcp[t] = f2bf(srw[(((size_t)n * 64 + ci) << 4) + r]);
}

// ---------------------------------------------------------------------------
// K6b: pack fc1/fc2 weights into CHUNK-contiguous bf16 layouts
// ---------------------------------------------------------------------------
__global__ __launch_bounds__(256) void k_wpack(const float* __restrict__ W1, const float* __restrict__ W2,
    unsigned short* __restrict__ W1q, unsigned short* __restrict__ W2q) {
  int t = blockIdx.x * 256 + threadIdx.x;
  if (t >= 65536) return;
  {
    int j = t & 7;
    int nl = (t >> 3) & 63;
    int s = (t >> 9) & 15;       // kc*4 + quad
    int hh = t >> 13;            // 0..7
    int k = (s >> 2) * 32 + (s & 3) * 8 + j;
    int n = hh * 64 + nl;
    W1q[t] = f2bf(W1[(size_t)k * 512 + n]);
  }
  {
    int j = t & 7;
    int n = (t >> 3) & 127;
    int s = (t >> 10) & 7;       // kg*4 + quad
    int hh = t >> 13;            // 0..7
    int k = hh * 64 + (s >> 2) * 32 + (s & 3) * 8 + j;
    W2q[t] = f2bf(W2[(size_t)k * 128 + n]);
  }
}

// ---------------------------------------------------------------------------
// K6c: pack q_w [64][128] into B-frag bf16 layout (single 16KB tile).
// Wq[s=kc*4+quad][n][j] = q_w[(s>>2)*32+(s&3)*8+j][n].
// ---------------------------------------------------------------------------
__global__ __launch_bounds__(256) void k_wqp(const float* __restrict__ qw,
                                             unsigned short* __restrict__ Wq) {
  int t = blockIdx.x * 256 + threadIdx.x;
  if (t >= 8192) return;
  int j = t & 7;
  int n = (t >> 3) & 127;
  int s = t >> 10;              // 0..7  (kc*4 + quad)
  int k = (s >> 2) * 32 + (s & 3) * 8 + j;
  Wq[t] = f2bf(qw[(size_t)k * 128 + n]);
}

// ---------------------------------------------------------------------------
// K-QPROJ (ROUND-13 FIX): qb[53312,128] = xn[53312,64] @ q_w[64,128], MFMA.
// BUGFIX vs round-12: the 16KB weight tile is 1024 short8 vectors; staging
// must copy 4 per thread (round-12 copied only 2 -> upper half of sW was
// uninitialized garbage -> NaN through softmax).
// ---------------------------------------------------------------------------
__global__ __launch_bounds__(256) void k_qproj(
    const float* __restrict__ xn, const unsigned short* __restrict__ Wq,
    float* __restrict__ qb) {
  __shared__ __align__(16) unsigned short sW[8192];
  int bm = blockIdx.x * 64;
  int tid = threadIdx.x;
  int wv = tid >> 6, lane = tid & 63, quad = lane >> 4, l16 = lane & 15;

  // stage whole weight tile: 1024 short8, 4 per thread
  const short8* gw = (const short8*)Wq;
  short8* dw = (short8*)sW;
#pragma unroll
  for (int i = 0; i < 4; ++i) dw[i * 256 + tid] = gw[i * 256 + tid];

  // A-fragments from global (row = bm + wv*16 + l16; k = kc*32 + quad*8 + j)
  int row = bm + wv * 16 + l16;
  const float* arow = xn + (size_t)row * 64 + quad * 8;
  short8 af[2];
#pragma unroll
  for (int kc = 0; kc < 2; ++kc) {
    float4 a = *(const float4*)(arow + kc * 32);
    float4 c = *(const float4*)(arow + kc * 32 + 4);
    af[kc][0]=(short)f2bf(a.x); af[kc][1]=(short)f2bf(a.y);
    af[kc][2]=(short)f2bf(a.z); af[kc][3]=(short)f2bf(a.w);
    af[kc][4]=(short)f2bf(c.x); af[kc][5]=(short)f2bf(c.y);
    af[kc][6]=(short)f2bf(c.z); af[kc][7]=(short)f2bf(c.w);
  }
  __syncthreads();

  f32x4 acc[8];
#pragma unroll
  for (int ct = 0; ct < 8; ++ct) acc[ct] = (f32x4){0.f, 0.f, 0.f, 0.f};
#pragma unroll
  for (int kc = 0; kc < 2; ++kc) {
    int s = kc * 4 + quad;
#pragma unroll
    for (int ct = 0; ct < 8; ++ct) {
      short8 bf = *(const short8*)&sW[(s * 128 + ct * 16 + l16) << 3];
      acc[ct] = __builtin_amdgcn_mfma_f32_16x16x32_bf16(af[kc], bf, acc[ct], 0, 0, 0);
    }
  }
#pragma unroll
  for (int ct = 0; ct < 8; ++ct)
#pragma unroll
    for (int r = 0; r < 4; ++r) {
      int orow = bm + wv * 16 + quad * 4 + r;
      int col = ct * 16 + l16;
      qb[(size_t)orow * 128 + col] = acc[ct][r];
    }
}

// ---------------------------------------------------------------------------
// K-CONV: xs_n = LN64(P @ wt + sr_b) -- LN fused into epilogue.
// ---------------------------------------------------------------------------
__global__ __launch_bounds__(256) void k_conv(
    const float* __restrict__ P, const unsigned short* __restrict__ Wcp,
    const float* __restrict__ bias, const float* __restrict__ sg,
    const float* __restrict__ sb, float* __restrict__ xsn) {
  __shared__ __align__(16) unsigned short sA[64 * 128];
  __shared__ __align__(16) unsigned short sW[8192];
  int bm = blockIdx.x * 64;
  int tid = threadIdx.x;
  int wv = tid >> 6, lane = tid & 63, quad = lane >> 4, l16 = lane & 15;

  const short8* gw = (const short8*)Wcp;
  short8* dw = (short8*)sW;

  short8 rw[4];
  float4 fa[4][2];
#pragma unroll
  for (int i = 0; i < 4; ++i) rw[i] = gw[i * 256 + tid];
#pragma unroll
  for (int i = 0; i < 4; ++i) {
    int u = i * 256 + tid;
    int row = u >> 4, ck = u & 15;
    const float* src = P + (size_t)(bm + row) * 1024 + ck * 8;
    fa[i][0] = *(const float4*)src;
    fa[i][1] = *(const float4*)(src + 4);
  }

  f32x4 acc[4];
#pragma unroll
  for (int ct = 0; ct < 4; ++ct) acc[ct] = (f32x4){0.f, 0.f, 0.f, 0.f};

  for (int ch = 0; ch < 8; ++ch) {
#pragma unroll
    for (int i = 0; i < 4; ++i) {
      dw[i * 256 + tid] = rw[i];
      int u = i * 256 + tid;
      int row = u >> 4, ck = u & 15;
      short8 p;
      p[0]=(short)f2bf(fa[i][0].x); p[1]=(short)f2bf(fa[i][0].y);
      p[2]=(short)f2bf(fa[i][0].z); p[3]=(short)f2bf(fa[i][0].w);
      p[4]=(short)f2bf(fa[i][1].x); p[5]=(short)f2bf(fa[i][1].y);
      p[6]=(short)f2bf(fa[i][1].z); p[7]=(short)f2bf(fa[i][1].w);
      *(short8*)&sA[row * 128 + (((ck ^ row) & 15) << 3)] = p;
    }
    __syncthreads();   // chunk visible
    if (ch < 7) {
      int wbase = (ch + 1) * 1024;
#pragma unroll
      for (int i = 0; i < 4; ++i) rw[i] = gw[wbase + i * 256 + tid];
#pragma unroll
      for (int i = 0; i < 4; ++i) {
        int u = i * 256 + tid;
        int row = u >> 4, ck = u & 15;
        const float* src = P + (size_t)(bm + row) * 1024 + (ch + 1) * 128 + ck * 8;
        fa[i][0] = *(const float4*)src;
        fa[i][1] = *(const float4*)(src + 4);
      }
    }
#pragma unroll
    for (int kc = 0; kc < 4; ++kc) {
      int row = wv * 16 + l16;
      int ck = kc * 4 + quad;
      short8 af = *(const short8*)&sA[row * 128 + (((ck ^ row) & 15) << 3)];
      int s = kc * 4 + quad;
#pragma unroll
      for (int ct = 0; ct < 4; ++ct) {
        short8 bf = *(const short8*)&sW[(s * 64 + ct * 16 + l16) << 3];
        acc[ct] = __builtin_amdgcn_mfma_f32_16x16x32_bf16(af, bf, acc[ct], 0, 0, 0);
      }
    }
    __syncthreads();   // all waves done reading before next commit
  }
  // epilogue: + bias, fused LN64, write xs_n
  float vv[4][4];
  float rsum[4], rss[4];
#pragma unroll
  for (int r = 0; r < 4; ++r) { rsum[r] = 0.f; rss[r] = 0.f; }
#pragma unroll
  for (int ct = 0; ct < 4; ++ct)
#pragma unroll
    for (int r = 0; r < 4; ++r) {
      float v = acc[ct][r] + bias[ct * 16 + l16];
      vv[ct][r] = v;
      rsum[r] += v;
      rss[r] += v * v;
    }
#pragma unroll
  for (int m = 1; m < 16; m <<= 1)
#pragma unroll
    for (int r = 0; r < 4; ++r) {
      rsum[r] += __shfl_xor(rsum[r], m);
      rss[r]  += __shfl_xor(rss[r], m);
    }
  float mean[4], rsl[4];
#pragma unroll
  for (int r = 0; r < 4; ++r) {
    mean[r] = rsum[r] * (1.f/64.f);
    float var = rss[r] * (1.f/64.f) - mean[r] * mean[r];
    rsl[r] = rsqrtf(var + LN_EPS);
  }
#pragma unroll
  for (int ct = 0; ct < 4; ++ct)
#pragma unroll
    for (int r = 0; r < 4; ++r) {
      int row = bm + wv * 16 + quad * 4 + r;
      int col = ct * 16 + l16;
      xsn[(size_t)row * 64 + col] = (vv[ct][r] - mean[r]) * rsl[r] * sg[col] + sb[col];
    }
}

// ---------------------------------------------------------------------------
// Tiled fp32 GEMM: C[M,N] = A[M,K] @ B[K,N] (+bias)(+add)
// ---------------------------------------------------------------------------
__global__ __launch_bounds__(256) void k_gemm(
    const float* __restrict__ A, const float* __restrict__ Bw,
    const float* __restrict__ bias, const float* __restrict__ add,
    float* __restrict__ Cout, int M, int N, int K) {
  __shared__ float sA[16][68];
  __shared__ float sB[16][64];
  int bm = blockIdx.x * 64, bn = blockIdx.y * 64;
  int tid = threadIdx.x;
  int tx = tid & 15, ty = tid >> 4;
  float acc[4][4] = {{0.f}};
  for (int k0 = 0; k0 < K; k0 += 16) {
    int e = tid << 2;
    int am = e >> 4, ak = e & 15;
    float4 a4 = *(const float4*)(A + (size_t)(bm + am) * K + k0 + ak);
    sA[ak + 0][am] = a4.x; sA[ak + 1][am] = a4.y; sA[ak + 2][am] = a4.z; sA[ak + 3][am] = a4.w;
    int bk = e >> 6, nn = e & 63;
    float4 b4 = *(const float4*)(Bw + (size_t)(k0 + bk) * N + bn + nn);
    *(float4*)&sB[bk][nn] = b4;
    __syncthreads();
#pragma unroll
    for (int kk = 0; kk < 16; ++kk) {
      float a[4], bb[4];
#pragma unroll
      for (int i = 0; i < 4; ++i) a[i] = sA[kk][ty * 4 + i];
#pragma unroll
      for (int i = 0; i < 4; ++i) bb[i] = sB[kk][tx * 4 + i];
#pragma unroll
      for (int i = 0; i < 4; ++i)
#pragma unroll
        for (int jj = 0; jj < 4; ++jj) acc[i][jj] += a[i] * bb[jj];
    }
    __syncthreads();
  }
#pragma unroll
  for (int i = 0; i < 4; ++i) {
    int row = bm + ty * 4 + i;
#pragma unroll
    for (int jj = 0; jj < 4; ++jj) {
      int col = bn + tx * 4 + jj;
      float v = acc[i][jj];
      if (bias) v += bias[col];
      if (add) v += add[(size_t)row * N + col];
      Cout[(size_t)row * N + col] = v;
    }
  }
}

// ---------------------------------------------------------------------------
// K-X2: fused  out = xd@fc_w + fc_b + (ob@proj_w + proj_b).
// ---------------------------------------------------------------------------
__global__ __launch_bounds__(256) void k_x2(
    const float* __restrict__ ob, const float* __restrict__ pw, const float* __restrict__ pb,
    const float* __restrict__ xd, const float* __restrict__ fw, const float* __restrict__ fb,
    float* __restrict__ out) {
  __shared__ float sA[16][68];
  __shared__ float sB[16][64];
  int bm = blockIdx.x * 64, bn = blockIdx.y * 64;
  int tid = threadIdx.x;
  int tx = tid & 15, ty = tid >> 4;
  int e = tid << 2;
  int am = e >> 4, ak = e & 15;
  int bk = e >> 6, nn = e & 63;
  float accP[4][4] = {{0.f}};
  // phase 1: ob @ proj_w, K = 128
  for (int k0 = 0; k0 < 128; k0 += 16) {
    float4 a4 = *(const float4*)(ob + (size_t)(bm + am) * 128 + k0 + ak);
    sA[ak + 0][am] = a4.x; sA[ak + 1][am] = a4.y; sA[ak + 2][am] = a4.z; sA[ak + 3][am] = a4.w;
    float4 b4 = *(const float4*)(pw + (size_t)(k0 + bk) * 128 + bn + nn);
    *(float4*)&sB[bk][nn] = b4;
    __syncthreads();
#pragma unroll
    for (int kk = 0; kk < 16; ++kk) {
      float a[4], bb[4];
#pragma unroll
      for (int i = 0; i < 4; ++i) a[i] = sA[kk][ty * 4 + i];
#pragma unroll
      for (int i = 0; i < 4; ++i) bb[i] = sB[kk][tx * 4 + i];
#pragma unroll
      for (int i = 0; i < 4; ++i)
#pragma unroll
        for (int jj = 0; jj < 4; ++jj) accP[i][jj] += a[i] * bb[jj];
    }
    __syncthreads();
  }
  float accF[4][4] = {{0.f}};
  // phase 2: xd @ fc_w, K = 64
  for (int k0 = 0; k0 < 64; k0 += 16) {
    float4 a4 = *(const float4*)(xd + (size_t)(bm + am) * 64 + k0 + ak);
    sA[ak + 0][am] = a4.x; sA[ak + 1][am] = a4.y; sA[ak + 2][am] = a4.z; sA[ak + 3][am] = a4.w;
    float4 b4 = *(const float4*)(fw + (size_t)(k0 + bk) * 128 + bn + nn);
    *(float4*)&sB[bk][nn] = b4;
    __syncthreads();
#pragma unroll
    for (int kk = 0; kk < 16; ++kk) {
      float a[4], bb[4];
#pragma unroll
      for (int i = 0; i < 4; ++i) a[i] = sA[kk][ty * 4 + i];
#pragma unroll
      for (int i = 0; i < 4; ++i) bb[i] = sB[kk][tx * 4 + i];
#pragma unroll
      for (int i = 0; i < 4; ++i)
#pragma unroll
        for (int jj = 0; jj < 4; ++jj) accF[i][jj] += a[i] * bb[jj];
    }
    __syncthreads();
  }
#pragma unroll
  for (int i = 0; i < 4; ++i) {
    int row = bm + ty * 4 + i;
#pragma unroll
    for (int jj = 0; jj < 4; ++jj) {
      int col = bn + tx * 4 + jj;
      out[(size_t)row * 128 + col] = accF[i][jj] + fb[col] + (accP[i][jj] + pb[col]);
    }
  }
}

// ---------------------------------------------------------------------------
// K-MLP (round-10 form; stable 61.7us local floor -- do not touch).
// out += gelu(LN128(out)@W1+b1)@W2+b2, LN fused, A-frags in registers.
// ---------------------------------------------------------------------------
__global__ __launch_bounds__(512) void k_mlp(
    const float* __restrict__ A, const float* __restrict__ gg, const float* __restrict__ gb,
    const unsigned short* __restrict__ W1q, const float* __restrict__ b1,
    const unsigned short* __restrict__ W2q, const float* __restrict__ b2,
    float* __restrict__ out) {
  __shared__ __align__(16) unsigned short sW1[8192];
  __shared__ __align__(16) unsigned short sW2[8192];
  __shared__ __align__(16) unsigned short sH[8][16 * 64];
  int bm = blockIdx.x * 128;
  int tid = threadIdx.x;
  int wv = tid >> 6, lane = tid & 63, quad = lane >> 4, l16 = lane & 15;

  const short8* g1 = (const short8*)W1q;
  const short8* g2 = (const short8*)W2q;
  short8* d1 = (short8*)sW1;
  short8* d2 = (short8*)sW2;

  short8 r1[2], r2[2];
#pragma unroll
  for (int i = 0; i < 2; ++i) {
    r1[i] = g1[i * 512 + tid];
    r2[i] = g2[i * 512 + tid];
  }

  int row = bm + wv * 16 + l16;
  int rowc = row < NROW ? row : NROW - 1;
  const float* arow = A + (size_t)rowc * 128 + quad * 8;
  float av[4][8];
  float s = 0.f, ss = 0.f;
#pragma unroll
  for (int kc = 0; kc < 4; ++kc) {
    float4 a = *(const float4*)(arow + kc * 32);
    float4 c = *(const float4*)(arow + kc * 32 + 4);
    av[kc][0]=a.x; av[kc][1]=a.y; av[kc][2]=a.z; av[kc][3]=a.w;
    av[kc][4]=c.x; av[kc][5]=c.y; av[kc][6]=c.z; av[kc][7]=c.w;
    s += a.x+a.y+a.z+a.w + c.x+c.y+c.z+c.w;
    ss += a.x*a.x+a.y*a.y+a.z*a.z+a.w*a.w + c.x*c.x+c.y*c.y+c.z*c.z+c.w*c.w;
  }
  s += __shfl_xor(s, 16);  ss += __shfl_xor(ss, 16);
  s += __shfl_xor(s, 32);  ss += __shfl_xor(ss, 32);
  float m = s * (1.f/128.f);
  float var = ss * (1.f/128.f) - m * m;
  float rs = rsqrtf(var + LN_EPS);
  short8 af[4];
#pragma unroll
  for (int kc = 0; kc < 4; ++kc) {
    int c0 = kc * 32 + quad * 8;
    float4 ga = *(const float4*)(gg + c0);
    float4 gc = *(const float4*)(gg + c0 + 4);
    float4 ba = *(const float4*)(gb + c0);
    float4 bc = *(const float4*)(gb + c0 + 4);
    af[kc][0] = (short)f2bf((av[kc][0]-m)*rs*ga.x + ba.x);
    af[kc][1] = (short)f2bf((av[kc][1]-m)*rs*ga.y + ba.y);
    af[kc][2] = (short)f2bf((av[kc][2]-m)*rs*ga.z + ba.z);
    af[kc][3] = (short)f2bf((av[kc][3]-m)*rs*ga.w + ba.w);
    af[kc][4] = (short)f2bf((av[kc][4]-m)*rs*gc.x + bc.x);
    af[kc][5] = (short)f2bf((av[kc][5]-m)*rs*gc.y + bc.y);
    af[kc][6] = (short)f2bf((av[kc][6]-m)*rs*gc.z + bc.z);
    af[kc][7] = (short)f2bf((av[kc][7]-m)*rs*gc.w + bc.w);
  }

  f32x4 oacc[8];
#pragma unroll
  for (int ct = 0; ct < 8; ++ct) oacc[ct] = (f32x4){0.f, 0.f, 0.f, 0.f};

  for (int hh = 0; hh < 8; ++hh) {
#pragma unroll
    for (int i = 0; i < 2; ++i) {
      d1[i * 512 + tid] = r1[i];
      d2[i * 512 + tid] = r2[i];
    }
    __syncthreads();
    if (hh < 7) {
      int base = (hh + 1) * 1024;
#pragma unroll
      for (int i = 0; i < 2; ++i) {
        r1[i] = g1[base + i * 512 + tid];
        r2[i] = g2[base + i * 512 + tid];
      }
    }
    f32x4 acc1[4];
#pragma unroll
    for (int ct = 0; ct < 4; ++ct) acc1[ct] = (f32x4){0.f, 0.f, 0.f, 0.f};
#pragma unroll
    for (int kc = 0; kc < 4; ++kc) {
      int sidx = kc * 4 + quad;
#pragma unroll
      for (int ct = 0; ct < 4; ++ct) {
        short8 bf = *(const short8*)&sW1[(sidx * 64 + ct * 16 + l16) << 3];
        acc1[ct] = __builtin_amdgcn_mfma_f32_16x16x32_bf16(af[kc], bf, acc1[ct], 0, 0, 0);
      }
    }
#pragma unroll
    for (int ct = 0; ct < 4; ++ct)
#pragma unroll
      for (int r = 0; r < 4; ++r) {
        float v = acc1[ct][r] + b1[hh * 64 + ct * 16 + l16];
        v = gelu_fast(v);
        int rit = quad * 4 + r;
        int col = ct * 16 + l16;
        int ck = (col >> 3) ^ (rit & 7);
        sH[wv][rit * 64 + ((ck & 7) << 3) + (col & 7)] = f2bf(v);
      }
#pragma unroll
    for (int kg = 0; kg < 2; ++kg) {
      int ckh = kg * 4 + quad;
      short8 hf = *(const short8*)&sH[wv][l16 * 64 + (((ckh ^ (l16 & 7)) & 7) << 3)];
      int sidx = kg * 4 + quad;
#pragma unroll
      for (int ct = 0; ct < 8; ++ct) {
        short8 bf = *(const short8*)&sW2[(sidx * 128 + ct * 16 + l16) << 3];
        oacc[ct] = __builtin_amdgcn_mfma_f32_16x16x32_bf16(hf, bf, oacc[ct], 0, 0, 0);
      }
    }
    __syncthreads();
  }
#pragma unroll
  for (int ct = 0; ct < 8; ++ct)
#pragma unroll
    for (int r = 0; r < 4; ++r) {
      int orow = bm + wv * 16 + quad * 4 + r;
      int col = ct * 16 + l16;
      if (orow < NROW)
        out[(size_t)orow * 128 + col] += oacc[ct][r] + b2[col];
    }
}

// ---------------------------------------------------------------------------
// K7: MFMA attention (round-10 form: 31KB LDS, high residency).
// ---------------------------------------------------------------------------
__global__ __launch_bounds__(256) void k_attn(const float* __restrict__ q,
    const float* __restrict__ kg, const float* __restrict__ vg, float* __restrict__ o) {
  __shared__ __align__(16) unsigned short ldsKP[14848];
  __shared__ __align__(16) unsigned short ldsV[16128];
  int blk = blockIdx.x;
  int chunk = blk % 14;
  int bh = blk / 14;
  int h = bh & 1, b = bh >> 1;
  int tid = threadIdx.x;
  int wv = tid >> 6, lane = tid & 63;
  int quad = lane >> 4, l16 = lane & 15;

  const float* kb = kg + (size_t)b * NS * 128 + h * 64;
  const float* vb = vg + (size_t)b * NS * 128 + h * 64;

  for (int t = tid; t < KPAD * 8; t += 256) {
    int key = t >> 3, ck = t & 7;
    short8 pk, pv;
    if (key < NS) {
      const float* ksrc = kb + (size_t)key * 128 + ck * 8;
      const float* vsrc = vb + (size_t)key * 128 + ck * 8;
      float4 a = *(const float4*)ksrc;
      float4 c = *(const float4*)(ksrc + 4);
      pk[0]=(short)f2bf(a.x); pk[1]=(short)f2bf(a.y); pk[2]=(short)f2bf(a.z); pk[3]=(short)f2bf(a.w);
      pk[4]=(short)f2bf(c.x); pk[5]=(short)f2bf(c.y); pk[6]=(short)f2bf(c.z); pk[7]=(short)f2bf(c.w);
      float4 e = *(const float4*)vsrc;
      float4 g = *(const float4*)(vsrc + 4);
      pv[0]=(short)f2bf(e.x); pv[1]=(short)f2bf(e.y); pv[2]=(short)f2bf(e.z); pv[3]=(short)f2bf(e.w);
      pv[4]=(short)f2bf(g.x); pv[5]=(short)f2bf(g.y); pv[6]=(short)f2bf(g.z); pv[7]=(short)f2bf(g.w);
    } else {
      pk = (short8)0; pv = (short8)0;
    }
    *(short8*)&ldsKP[key * 64 + ((ck ^ (key & 7)) << 3)] = pk;
    *(short8*)&ldsV[key * 72 + ck * 8] = pv;
  }

  int qrow = chunk * 64 + wv * 16 + l16;
  int qrowc = qrow < ND ? qrow : ND - 1;
  const float* qsrc = q + ((size_t)b * ND + qrowc) * 128 + h * 64 + quad * 8;
  short8 aq0, aq1;
  {
    float4 a = *(const float4*)qsrc;
    float4 c = *(const float4*)(qsrc + 4);
    aq0[0]=(short)f2bf(a.x); aq0[1]=(short)f2bf(a.y); aq0[2]=(short)f2bf(a.z); aq0[3]=(short)f2bf(a.w);
    aq0[4]=(short)f2bf(c.x); aq0[5]=(short)f2bf(c.y); aq0[6]=(short)f2bf(c.z); aq0[7]=(short)f2bf(c.w);
    float4 e = *(const float4*)(qsrc + 32);
    float4 g = *(const float4*)(qsrc + 36);
    aq1[0]=(short)f2bf(e.x); aq1[1]=(short)f2bf(e.y); aq1[2]=(short)f2bf(e.z); aq1[3]=(short)f2bf(e.w);
    aq1[4]=(short)f2bf(g.x); aq1[5]=(short)f2bf(g.y); aq1[6]=(short)f2bf(g.z); aq1[7]=(short)f2bf(g.w);
  }
  __syncthreads();

  f32x4 acc[14];
#pragma unroll
  for (int ct = 0; ct < 14; ++ct) {
    int key = ct * 16 + l16;
    short8 bk0 = *(const short8*)&ldsKP[key * 64 + ((quad ^ (key & 7)) << 3)];
    short8 bk1 = *(const short8*)&ldsKP[key * 64 + (((4 + quad) ^ (key & 7)) << 3)];
    f32x4 z = {0.f, 0.f, 0.f, 0.f};
    z = __builtin_amdgcn_mfma_f32_16x16x32_bf16(aq0, bk0, z, 0, 0, 0);
    z = __builtin_amdgcn_mfma_f32_16x16x32_bf16(aq1, bk1, z, 0, 0, 0);
    acc[ct] = z;
  }

  const float scale = 0.17677669529663687f;  // 32^-0.5
  float rmax[4] = {-1e30f, -1e30f, -1e30f, -1e30f};
#pragma unroll
  for (int ct = 0; ct < 14; ++ct) {
    bool msk = (ct * 16 + l16) >= NS;
#pragma unroll
    for (int r = 0; r < 4; ++r) {
      float sv = msk ? -1e30f : acc[ct][r] * scale;
      acc[ct][r] = sv;
      rmax[r] = fmaxf(rmax[r], sv);
    }
  }
#pragma unroll
  for (int m = 1; m < 16; m <<= 1)
#pragma unroll
    for (int r = 0; r < 4; ++r) rmax[r] = fmaxf(rmax[r], __shfl_xor(rmax[r], m));
  float rsum[4] = {0.f, 0.f, 0.f, 0.f};
#pragma unroll
  for (int ct = 0; ct < 14; ++ct)
#pragma unroll
    for (int r = 0; r < 4; ++r) {
      float e = __expf(acc[ct][r] - rmax[r]);
      acc[ct][r] = e;
      rsum[r] += e;
    }
#pragma unroll
  for (int m = 1; m < 16; m <<= 1)
#pragma unroll
    for (int r = 0; r < 4; ++r) rsum[r] += __shfl_xor(rsum[r], m);
  float rinv[4];
#pragma unroll
  for (int r = 0; r < 4; ++r) rinv[r] = 1.f / rsum[r];

  __syncthreads();

#pragma unroll
  for (int ct = 0; ct < 14; ++ct)
#pragma unroll
    for (int r = 0; r < 4; ++r) {
      int prow = wv * 16 + quad * 4 + r;
      ldsKP[prow * 232 + ct * 16 + l16] = f2bf(acc[ct][r] * rinv[r]);
    }
  __syncthreads();

  f32x4 oacc[4];
#pragma unroll
  for (int ot = 0; ot < 4; ++ot) oacc[ot] = (f32x4){0.f, 0.f, 0.f, 0.f};
#pragma unroll
  for (int kc = 0; kc < 7; ++kc) {
    short8 ap = *(const short8*)&ldsKP[(wv * 16 + l16) * 232 + kc * 32 + quad * 8];
    int keybase = kc * 32 + quad * 8;
#pragma unroll
    for (int ot = 0; ot < 4; ++ot) {
      int dcol = ot * 16 + l16;
      short8 bv;
#pragma unroll
      for (int j = 0; j < 8; ++j) bv[j] = (short)ldsV[(keybase + j) * 72 + dcol];
      oacc[ot] = __builtin_amdgcn_mfma_f32_16x16x32_bf16(ap, bv, oacc[ot], 0, 0, 0);
    }
  }

#pragma unroll
  for (int ot = 0; ot < 4; ++ot)
#pragma unroll
    for (int r = 0; r < 4; ++r) {
      int rowg = chunk * 64 + wv * 16 + quad * 4 + r;
      if (rowg < ND)
        o[((size_t)b * ND + rowg) * 128 + h * 64 + ot * 16 + l16] = oacc[ot][r];
    }
}

// ---------------------------------------------------------------------------
// K8: bilinear grid-sample of pos_embed at pos_down, accumulate into out
// ---------------------------------------------------------------------------
__global__ __launch_bounds__(256) void k_posfeat(const float* __restrict__ pd,
    const float* __restrict__ pe, float* __restrict__ out) {
  int t = blockIdx.x * 256 + threadIdx.x;
  int row = t >> 5, lane = t & 31;
  if (row >= B_ * ND) return;
  float gx = pd[(size_t)2*row] * 2.f - 1.f;
  float gy = pd[(size_t)2*row+1] * 2.f - 1.f;
  float ix = ((gx + 1.f) * 56.f - 1.f) * 0.5f;
  float iy = ((gy + 1.f) * 56.f - 1.f) * 0.5f;
  float x0 = floorf(ix), y0 = floorf(iy);
  float wx1 = ix - x0, wy1 = iy - y0;
  float wx0 = 1.f - wx1, wy0 = 1.f - wy1;
  float4 acc = make_float4(0.f, 0.f, 0.f, 0.f);
#pragma unroll
  for (int cy = 0; cy < 2; ++cy) {
#pragma unroll
    for (int cx = 0; cx < 2; ++cx) {
      float xc = x0 + (float)cx, yc = y0 + (float)cy;
      float wgt = (cx ? wx1 : wx0) * (cy ? wy1 : wy0);
      bool valid = (xc >= 0.f) && (xc < 56.f) && (yc >= 0.f) && (yc < 56.f);
      if (valid) {
        int lin = (int)yc * 56 + (int)xc;
        float4 pv = ((const float4*)(pe + (size_t)lin * 128))[lane];
        acc.x += wgt * pv.x; acc.y += wgt * pv.y;
        acc.z += wgt * pv.z; acc.w += wgt * pv.w;
      }
    }
  }
  float4* op = (float4*)(out + (size_t)row * 128) + lane;
  float4 cur = *op;
  cur.x += acc.x; cur.y += acc.y; cur.z += acc.z; cur.w += acc.w;
  *op = cur;
}

// ---------------------------------------------------------------------------
// launcher
// ---------------------------------------------------------------------------
extern "C" void kernel_launch(void* const* d_in, const int* in_sizes, int n_in,
                              void* d_out, int out_size, void* d_ws, size_t ws_size,
                              hipStream_t stream) {
  const float* x      = (const float*)d_in[0];
  const float* pos    = (const float*)d_in[1];
  const float* pe     = (const float*)d_in[2];
  const float* nu     = (const float*)d_in[3];
  const float* norm_g = (const float*)d_in[4];
  const float* norm_b = (const float*)d_in[5];
  const float* conf_w = (const float*)d_in[6];
  const float* conf_b = (const float*)d_in[7];
  const float* n1g    = (const float*)d_in[8];
  const float* n1b    = (const float*)d_in[9];
  const float* q_w    = (const float*)d_in[10];
  const float* k_w    = (const float*)d_in[11];
  const float* v_w    = (const float*)d_in[12];
  const float* proj_w = (const float*)d_in[13];
  const float* proj_b = (const float*)d_in[14];
  const float* sr_w   = (const float*)d_in[15];
  const float* sr_b   = (const float*)d_in[16];
  const float* srn_g  = (const float*)d_in[17];
  const float* srn_b  = (const float*)d_in[18];
  const float* fc_w   = (const float*)d_in[19];
  const float* fc_b   = (const float*)d_in[20];
  const float* n2g    = (const float*)d_in[21];
  const float* n2b    = (const float*)d_in[22];
  const float* fc1_w  = (const float*)d_in[23];
  const float* fc1_b  = (const float*)d_in[24];
  const float* fc2_w  = (const float*)d_in[25];
  const float* fc2_b  = (const float*)d_in[26];

  char* ws = (char*)d_ws;
  // workspace layout (bytes); total 190,578,688 (unchanged)
  double*         scores = (double*)(ws + 0);                //  1,580,544
  int*            idx    = (int*)(ws + 1605632);             //    200,704
  float*          xd     = (float*)(ws + 1835008);           // 13,647,872
  float*          xn     = (float*)(ws + 15728640);          // 13,647,872
  float*          pd     = (float*)(ws + 29491200);          //    426,496
  float*          qb     = (float*)(ws + 30408704);          // 27,295,744; T alias; later q
  float*          ob     = (float*)(ws + 58720256);          // 27,295,744; T tail alias
  unsigned short* Wcp    = (unsigned short*)(ws + 86507520); //    131,072 (conv weights, bf16 packed)
  unsigned short* W1p    = (unsigned short*)(ws + 86769664); //    131,072
  unsigned short* W2p    = (unsigned short*)(ws + 86900736); //    131,072 (ends 87,031,808)
  char*           big    = ws + 87031808;                    // 103,546,880 region
  float*          S      = (float*)big;                      // 52,183,040 (dead after transpose)
  float*          T      = qb;                               // 51,380,224 channel planes (dead after filter2)
  float*          Kc     = (float*)(big + 52183040);         //  7,225,344 coefficient planes (dead after filter2)
  float*          P      = (float*)big;                      // 51,380,224 (reuses dead S; dead after conv)
  float*          xs_n   = (float*)(big + 62619648);         //  3,211,264
  float*          kbuf   = (float*)(big + 65830912);         //  6,422,528
  float*          vbuf   = (float*)(big + 72253440);         //  6,422,528 (ends 78,675,968)
  float*          Mbuf   = (float*)(big + 78675968);         //    802,816 mask plane (dead after coef)
  int*            head   = (int*)(big + 79478784);           //    802,816 (dead after accum)
  int*            nxt    = (int*)(big + 80281600);           //    802,816 (ends 81,084,416)
  unsigned short* Wqp    = (unsigned short*)(big + 81084416);//     16,384 (q_w packed)
  float*          out    = (float*)d_out;

  // 1) f64 conf+gumbel scores
  k_conf<<<(B_ * N_) / 256, 256, 0, stream>>>(x, norm_g, norm_b, conf_w, conf_b, nu, scores);
  // 2) top-784 per batch: exact counting-sort rank (one block per batch)
  k_topk2<<<B_, 256, 0, stream>>>(scores, idx);
  // 3) gather + LN(norm1)
  k_gather_ln<<<(B_ * ND + 255) / 256, 256, 0, stream>>>(x, pos, idx, n1g, n1b, xd, xn, pd);
  // 4) token2map: per-pixel linked lists then gather-accumulate
  hipMemsetAsync(head, 0xFF, (size_t)B_ * HW * sizeof(int), stream);
  k_link<<<(B_ * N_ + 255) / 256, 256, 0, stream>>>(pos, head, nxt);
  k_accum<<<(B_ * HW * 64) / 256, 256, 0, stream>>>(x, n1g, n1b, head, nxt, S);
  // 5) gaussian reconstruct: transpose (+mask plane), coef, 3x3 conv
  k_transpose<<<BHW / 64, 256, 0, stream>>>(S, T, Mbuf);
  k_coef<<<BHW / 256, 256, 0, stream>>>(Mbuf, Kc);
  k_filter2<<<B_ * 64, 256, 0, stream>>>(T, Kc, P);
  // 6) weight packing (conv + MLP + qproj); MFMA conv-as-GEMM with fused LN64
  k_wtp<<<65536 / 256, 256, 0, stream>>>(sr_w, Wcp);
  k_wpack<<<65536 / 256, 256, 0, stream>>>(fc1_w, fc2_w, W1p, W2p);
  k_wqp<<<8192 / 256, 256, 0, stream>>>(q_w, Wqp);
  k_conv<<<B_ * NS / 64, 256, 0, stream>>>(P, Wcp, sr_b, srn_g, srn_b, xs_n);
  // 7) k, v (fp32 GEMM, small) and q (MFMA, big) projections
  dim3 g_kv(B_ * NS / 64, 2);
  k_gemm<<<g_kv, 256, 0, stream>>>(xs_n, k_w, nullptr, nullptr, kbuf, B_ * NS, 128, 64);
  k_gemm<<<g_kv, 256, 0, stream>>>(xs_n, v_w, nullptr, nullptr, vbuf, B_ * NS, 128, 64);
  k_qproj<<<NROW / 64, 256, 0, stream>>>(xn, Wqp, qb);
  // 8) attention (MFMA bf16)
  k_attn<<<B_ * 2 * 14, 256, 0, stream>>>(qb, kbuf, vbuf, ob);
  // 9) fused x2 = xd@fc_w + fc_b + (ob@proj_w + proj_b) -> d_out
  dim3 g_row(B_ * ND / 64, 2);
  k_x2<<<g_row, 256, 0, stream>>>(ob, proj_w, proj_b, xd, fc_w, fc_b, out);
  // 10) MLP: fused LN128 + fc1 + gelu + fc2 (128-row 8-wave blocks)
  k_mlp<<<(NROW + 127) / 128, 512, 0, stream>>>(out, n2g, n2b, W1p, fc1_b, W2p, fc2_b, out);
  // 11) + pos_feat (bilinear grid sample)
  k_posfeat<<<(B_ * ND * 32) / 256, 256, 0, stream>>>(pd, pe, out);
}

// Round 14
// 494.070 us; speedup vs baseline: 1.1122x; 1.0703x over previous
//
#include <hip/hip_runtime.h>
#include <math.h>

#define DEVINL __device__ __forceinline__

constexpr int B_ = 64;
constexpr int N_ = 3136;
constexpr int C_ = 64;        // DIM
constexpr int NG = 49;        // N_grid
constexpr int NSAMP = 784;    // SAMPLE_NUM
constexpr int ND = NG + NSAMP;     // 833
constexpr int NREST = N_ - NG;     // 3087
constexpr int H_ = 56, W_ = 56;
constexpr int HW = H_ * W_;        // 3136
constexpr int BHW = B_ * HW;       // 200704
constexpr int NS = 14 * 14;        // 196 kv tokens
constexpr int KPAD = 224;          // 196 padded to 7*32
constexpr int NROW = B_ * ND;      // 53312 = 833 * 64 exactly
constexpr float LN_EPS = 1e-5f;
constexpr float EPS6 = 1e-6f;

typedef __attribute__((ext_vector_type(8))) short short8;
typedef __attribute__((ext_vector_type(4))) float f32x4;

DEVINL unsigned short f2bf(float f) {
  unsigned int u = __float_as_uint(f);
  unsigned int r = u + 0x7FFFu + ((u >> 16) & 1u);
  return (unsigned short)(r >> 16);
}

// Fast exact-GELU: erf via Abramowitz-Stegun 7.1.26 (|err| <= 1.5e-7).
DEVINL float gelu_fast(float v) {
  float x = v * 0.70710678118654752f;
  float ax = fabsf(x);
  float t = 1.f / fmaf(0.3275911f, ax, 1.f);
  float poly = t * fmaf(t, fmaf(t, fmaf(t, fmaf(t, 1.061405429f, -1.453152027f),
                        1.421413741f), -0.284496736f), 0.254829592f);
  float e = 1.f - poly * __expf(-x * x);
  float erfv = copysignf(e, x);
  return 0.5f * v * (1.f + erfv);
}

// ---------------------------------------------------------------------------
// K1: conf scores in FP64 (discrete top-k decision must match f64 np ref)
// ---------------------------------------------------------------------------
__global__ __launch_bounds__(256) void k_conf(
    const float* __restrict__ x, const float* __restrict__ ng, const float* __restrict__ nb,
    const float* __restrict__ cw, const float* __restrict__ cb,
    const float* __restrict__ nu, double* __restrict__ scores) {
  int t = blockIdx.x * 256 + threadIdx.x;
  if (t >= B_ * N_) return;
  int b = t / N_, n = t - b * N_;
  if (n < NG) return;
  const float4* row = (const float4*)(x + (size_t)t * C_);
  float v[C_];
#pragma unroll
  for (int i = 0; i < 16; ++i) {
    float4 r = row[i];
    v[4*i] = r.x; v[4*i+1] = r.y; v[4*i+2] = r.z; v[4*i+3] = r.w;
  }
  double sd = 0.0;
#pragma unroll
  for (int i = 0; i < C_; ++i) sd += (double)v[i];
  double md = sd * (1.0/64.0);
  double vd = 0.0;
#pragma unroll
  for (int i = 0; i < C_; ++i) { double d = (double)v[i] - md; vd += d * d; }
  vd *= (1.0/64.0);
  double rsd = 1.0 / sqrt(vd + 1e-5);
  double conf = (double)cb[0];
#pragma unroll
  for (int i = 0; i < C_; ++i) {
    double xnv = ((double)v[i] - md) * rsd;
    conf += (xnv * (double)ng[i] + (double)nb[i]) * (double)cw[i];
  }
  double u = (double)nu[(size_t)b * NREST + (n - NG)];
  double noise = -log(-log(u + 1e-6) + 1e-6);
  scores[(size_t)b * NREST + (n - NG)] = conf + noise;
}

// ---------------------------------------------------------------------------
// K2: exact top-784 via counting-sort rank. One block per batch.
// ---------------------------------------------------------------------------
constexpr int NB = 2048;

__global__ __launch_bounds__(256) void k_topk2(const double* __restrict__ scores,
                                               int* __restrict__ idx) {
  __shared__ double sk[NREST];              // 24,696 B
  __shared__ int hist[NB];                  //  8,192 B
  __shared__ int bstart[NB];                //  8,192 B
  __shared__ int fill[NB];                  //  8,192 B
  __shared__ unsigned short order[NREST];   //  6,174 B
  __shared__ float redmin[256], redmax[256];//  2,048 B
  __shared__ int scanbuf[256];              //  1,024 B   (~58.5 KB total)
  int b = blockIdx.x, tid = threadIdx.x;
  const double* sc = scores + (size_t)b * NREST;
  float lmin = 3.4e38f, lmax = -3.4e38f;
  for (int i = tid; i < NREST; i += 256) {
    double d = sc[i];
    sk[i] = d;
    float f = (float)d;
    lmin = fminf(lmin, f); lmax = fmaxf(lmax, f);
  }
  for (int i = tid; i < NB; i += 256) hist[i] = 0;
  redmin[tid] = lmin; redmax[tid] = lmax;
  __syncthreads();
  for (int s = 128; s > 0; s >>= 1) {
    if (tid < s) {
      redmin[tid] = fminf(redmin[tid], redmin[tid + s]);
      redmax[tid] = fmaxf(redmax[tid], redmax[tid + s]);
    }
    __syncthreads();
  }
  float fmn = redmin[0];
  float scale = (float)NB / fmaxf(redmax[0] - fmn, 1e-30f);
  // histogram
  for (int i = tid; i < NREST; i += 256) {
    float f = (float)sk[i];
    int bn = (int)((f - fmn) * scale);
    bn = bn < 0 ? 0 : (bn > NB - 1 ? NB - 1 : bn);
    atomicAdd(&hist[bn], 1);
  }
  __syncthreads();
  // suffix scan: bstart[bin] = sum over strictly-higher bins.
  int base = tid * 8;          // this thread owns bins [base, base+8)
  int s_t = 0;
#pragma unroll
  for (int i = 0; i < 8; ++i) s_t += hist[base + i];
  scanbuf[tid] = s_t;
  __syncthreads();
  int val = s_t;
  for (int off = 1; off < 256; off <<= 1) {
    int other = (tid + off < 256) ? scanbuf[tid + off] : 0;
    __syncthreads();
    val += other;
    scanbuf[tid] = val;
    __syncthreads();
  }
  int run = val - s_t;         // sum over threads t' > tid
#pragma unroll
  for (int i = 7; i >= 0; --i) {
    bstart[base + i] = run;
    run += hist[base + i];
  }
  __syncthreads();
  for (int i = tid; i < NB; i += 256) fill[i] = bstart[i];
  __syncthreads();
  // scatter element ids into bin-grouped order[]
  for (int i = tid; i < NREST; i += 256) {
    float f = (float)sk[i];
    int bn = (int)((f - fmn) * scale);
    bn = bn < 0 ? 0 : (bn > NB - 1 ? NB - 1 : bn);
    int pos = atomicAdd(&fill[bn], 1);
    order[pos] = (unsigned short)i;
  }
  __syncthreads();
  // exact rank = bstart[bin] + within-bin f64 rank; write winners
  for (int i = tid; i < NREST; i += 256) {
    double ke = sk[i];
    float f = (float)ke;
    int bn = (int)((f - fmn) * scale);
    bn = bn < 0 ? 0 : (bn > NB - 1 ? NB - 1 : bn);
    int st = bstart[bn], m = hist[bn];
    int r = st;
    for (int p = st; p < st + m; ++p) {
      int j = order[p];
      double kj = sk[j];
      r += (int)((kj > ke) | ((kj == ke) & (j < i)));
    }
    if (r < NSAMP) idx[(size_t)b * NSAMP + r] = i;
  }
}

// ---------------------------------------------------------------------------
// K3: gather x_down/pos_down rows; LayerNorm(x_down, norm1) -> xn
// ---------------------------------------------------------------------------
__global__ __launch_bounds__(256) void k_gather_ln(
    const float* __restrict__ x, const float* __restrict__ pos, const int* __restrict__ idx,
    const float* __restrict__ n1g, const float* __restrict__ n1b,
    float* __restrict__ xd, float* __restrict__ xn, float* __restrict__ pd) {
  int t = blockIdx.x * 256 + threadIdx.x;
  if (t >= B_ * ND) return;
  int b = t / ND, r = t - b * ND;
  int srcn = (r < NG) ? r : (NG + idx[(size_t)b * NSAMP + (r - NG)]);
  const float4* row = (const float4*)(x + ((size_t)b * N_ + srcn) * C_);
  float4* xdr = (float4*)(xd + (size_t)t * C_);
  float v[C_];
  float s = 0.f, ss = 0.f;
#pragma unroll
  for (int i = 0; i < 16; ++i) {
    float4 rr = row[i];
    xdr[i] = rr;
    v[4*i] = rr.x; v[4*i+1] = rr.y; v[4*i+2] = rr.z; v[4*i+3] = rr.w;
    s += rr.x + rr.y + rr.z + rr.w;
    ss += rr.x*rr.x + rr.y*rr.y + rr.z*rr.z + rr.w*rr.w;
  }
  float m = s * (1.f/64.f);
  float var = ss * (1.f/64.f) - m*m;
  float rs = rsqrtf(var + LN_EPS);
#pragma unroll
  for (int i = 0; i < C_; ++i)
    xn[(size_t)t * C_ + i] = (v[i] - m) * rs * n1g[i] + n1b[i];
  pd[(size_t)2*t]   = pos[((size_t)b * N_ + srcn) * 2];
  pd[(size_t)2*t+1] = pos[((size_t)b * N_ + srcn) * 2 + 1];
}

// ---------------------------------------------------------------------------
// K4a: build per-pixel token linked lists (1 atomicExch per token).
// ---------------------------------------------------------------------------
__global__ __launch_bounds__(256) void k_link(
    const float* __restrict__ pos, int* __restrict__ head, int* __restrict__ next) {
  int tok = blockIdx.x * 256 + threadIdx.x;
  if (tok >= B_ * N_) return;
  int b = tok / N_;
  double px = fmin(fmax((double)pos[(size_t)2*tok],   0.0), 1.0) * (double)(W_ - 1);
  double py = fmin(fmax((double)pos[(size_t)2*tok+1], 0.0), 1.0) * (double)(H_ - 1);
  int xi = (int)rint(px), yi = (int)rint(py);
  int p = b * HW + yi * W_ + xi;
  next[tok] = atomicExch(&head[p], tok);
}

// ---------------------------------------------------------------------------
// K4b: gather-accumulate. One WAVE per pixel, lane = channel.
// ---------------------------------------------------------------------------
__global__ __launch_bounds__(256) void k_accum(
    const float* __restrict__ x, const float* __restrict__ n1g, const float* __restrict__ n1b,
    const int* __restrict__ head, const int* __restrict__ next, float* __restrict__ S) {
  int gt = blockIdx.x * 256 + threadIdx.x;
  int p = gt >> 6, lane = gt & 63;
  if (p >= B_ * HW) return;
  float g = n1g[lane], bb = n1b[lane];
  float acc = 0.f, cnt = 0.f;
  int tok = head[p];
  while (tok >= 0) {
    float v = x[(size_t)tok * C_ + lane];
    float s = v, ss = v * v;
#pragma unroll
    for (int m = 32; m > 0; m >>= 1) {
      s += __shfl_xor(s, m);
      ss += __shfl_xor(ss, m);
    }
    float mean = s * (1.f/64.f);
    float var = ss * (1.f/64.f) - mean * mean;
    float rs = rsqrtf(var + LN_EPS);
    acc += (v - mean) * rs * g + bb;
    cnt += 1.f;
    tok = next[tok];
  }
  float* base = S + (size_t)p * 65;
  base[lane] = acc;
  if (lane == 0) base[64] = cnt;
}

// ---------------------------------------------------------------------------
// K5b: transpose S[p][65] -> channel planes T[b][c][HW] + mask plane M.
// ---------------------------------------------------------------------------
__global__ __launch_bounds__(256) void k_transpose(const float* __restrict__ S,
                                                   float* __restrict__ T,
                                                   float* __restrict__ M) {
  __shared__ float ls[64 * 65];
  int g0 = blockIdx.x * 64;            // global pixel base (batch-major)
  int b = g0 / HW, p0 = g0 - b * HW;
  const float4* src = (const float4*)(S + (size_t)g0 * 65);
  for (int i = threadIdx.x; i < (64 * 65) / 4; i += 256)
    *(float4*)&ls[i * 4] = src[i];
  __syncthreads();
  for (int i = threadIdx.x; i < 64 * 64; i += 256) {
    int c = i >> 6, px = i & 63;
    T[((size_t)(b * 64 + c)) * HW + p0 + px] = ls[px * 65 + c];
  }
  for (int i = threadIdx.x; i < 64; i += 256)
    M[(size_t)g0 + i] = ls[i * 65 + 64];
}

// ---------------------------------------------------------------------------
// K5a: per-pixel 3x3 coefficient planes, mask read from contiguous M plane.
// ---------------------------------------------------------------------------
__global__ __launch_bounds__(256) void k_coef(const float* __restrict__ M, float* __restrict__ Kc) {
  int t = blockIdx.x * 256 + threadIdx.x;
  if (t >= BHW) return;
  int b = t / HW, p = t - b * HW;
  int y = p / W_, x = p - y * W_;
  const float* Mb = M + (size_t)b * HW;
  const float e1 = 0.882496902584595f;   // exp(-1/8)
  const float e2 = 0.778800783071405f;   // exp(-1/4)
  const float Z = 1.f + 4.f * (e1 + e2);
  float m0 = Mb[p];
  float mb0 = m0 > 0.f ? 1.f : 0.f;
  float cfac = mb0 / (m0 + EPS6);
  float sc[9];
  float mi = 0.f;
  int q = 0;
#pragma unroll
  for (int dy = -1; dy <= 1; ++dy) {
#pragma unroll
    for (int dx = -1; dx <= 1; ++dx) {
      int ny = y + dy, nx = x + dx;
      bool in = (ny >= 0 && ny < H_ && nx >= 0 && nx < W_);
      float w = ((dx == 0 && dy == 0) ? 1.f : ((dx*dx + dy*dy) == 1 ? e1 : e2)) / Z;
      float mm = in ? Mb[ny * W_ + nx] : 0.f;
      float mb = mm > 0.f ? 1.f : 0.f;
      mi += w * mb;
      sc[q] = in ? (w * mb / (mm + EPS6)) : 0.f;
      ++q;
    }
  }
  float outer = (1.f - mb0) * ((mi > 0.f ? 1.f : 0.f) / (mi + EPS6));
#pragma unroll
  for (int qq = 0; qq < 9; ++qq) {
    float cq = outer * sc[qq];
    if (qq == 4) cq += cfac;
    Kc[(size_t)qq * BHW + t] = cq;
  }
}

// ---------------------------------------------------------------------------
// K5c: spatially-varying 3x3 conv on channel planes -> conv-patch layout P.
// ---------------------------------------------------------------------------
__global__ __launch_bounds__(256) void k_filter2(
    const float* __restrict__ T, const float* __restrict__ Kc, float* __restrict__ P) {
  int plane = blockIdx.x;              // b*64 + c
  int b = plane >> 6, c = plane & 63;
  int tid = threadIdx.x;
  const float* Tp = T + (size_t)plane * HW;
  const float* Kb = Kc + (size_t)b * HW;
  for (int p0 = 0; p0 < HW; p0 += 256) {
    int p = p0 + tid;
    if (p < HW) {
      int y = p / W_, x = p - y * W_;
      float acc = 0.f;
      int q = 0;
#pragma unroll
      for (int dy = -1; dy <= 1; ++dy) {
#pragma unroll
        for (int dx = -1; dx <= 1; ++dx) {
          int ny = y + dy; ny = ny < 0 ? 0 : (ny > H_ - 1 ? H_ - 1 : ny);
          int nx = x + dx; nx = nx < 0 ? 0 : (nx > W_ - 1 ? W_ - 1 : nx);
          acc += Kb[(size_t)q * BHW + p] * Tp[ny * W_ + nx];
          ++q;
        }
      }
      int j = (y >> 2) * 14 + (x >> 2);
      int colb = ((y & 3) << 2) + (x & 3);
      P[((size_t)(b * NS + j)) * 1024 + c * 16 + colb] = acc;
    }
  }
}

// ---------------------------------------------------------------------------
// K6: pack sr_w into chunk-contiguous bf16 B-frag layout for the conv GEMM.
// ---------------------------------------------------------------------------
__global__ __launch_bounds__(256) void k_wtp(const float* __restrict__ srw,
                                             unsigned short* __restrict__ Wcp) {
  int t = blockIdx.x * 256 + threadIdx.x;
  if (t >= 65536) return;
  int j = t & 7;
  int n = (t >> 3) & 63;        // co
  int s = (t >> 9) & 15;        // kc*4 + quad
  int ch = t >> 13;             // 0..7
  int k = ch * 128 + (s >> 2) * 32 + (s & 3) * 8 + j;
  int ci = k >> 4, r = k & 15;
  Wcp[t] = f2bf(srw[(((size_t)n * 64 + ci) << 4) + r]);
}

// ---------------------------------------------------------------------------
// K6b: pack fc1/fc2 weights into CHUNK-contiguous bf16 layouts
// ---------------------------------------------------------------------------
__global__ __launch_bounds__(256) void k_wpack(const float* __restrict__ W1, const float* __restrict__ W2,
    unsigned short* __restrict__ W1q, unsigned short* __restrict__ W2q) {
  int t = blockIdx.x * 256 + threadIdx.x;
  if (t >= 65536) return;
  {
    int j = t & 7;
    int nl = (t >> 3) & 63;
    int s = (t >> 9) & 15;       // kc*4 + quad
    int hh = t >> 13;            // 0..7
    int k = (s >> 2) * 32 + (s & 3) * 8 + j;
    int n = hh * 64 + nl;
    W1q[t] = f2bf(W1[(size_t)k * 512 + n]);
  }
  {
    int j = t & 7;
    int n = (t >> 3) & 127;
    int s = (t >> 10) & 7;       // kg*4 + quad
    int hh = t >> 13;            // 0..7
    int k = hh * 64 + (s >> 2) * 32 + (s & 3) * 8 + j;
    W2q[t] = f2bf(W2[(size_t)k * 128 + n]);
  }
}

// ---------------------------------------------------------------------------
// K6c: pack a [64][128] weight into B-frag bf16 layout (single 16KB tile).
// Wq[s=kc*4+quad][n][j] = w[(s>>2)*32+(s&3)*8+j][n].  Used for q_w/k_w/v_w.
// ---------------------------------------------------------------------------
__global__ __launch_bounds__(256) void k_wqp(const float* __restrict__ qw,
                                             unsigned short* __restrict__ Wq) {
  int t = blockIdx.x * 256 + threadIdx.x;
  if (t >= 8192) return;
  int j = t & 7;
  int n = (t >> 3) & 127;
  int s = t >> 10;              // 0..7  (kc*4 + quad)
  int k = (s >> 2) * 32 + (s & 3) * 8 + j;
  Wq[t] = f2bf(qw[(size_t)k * 128 + n]);
}

// ---------------------------------------------------------------------------
// K6d (ROUND-14): pack proj_w [128][128] into B-frag bf16 (32KB, K=128:
// s = kc*4+quad, kc 0..3) and fc_w [64][128] (16KB, K=64: kc 0..1).
// ---------------------------------------------------------------------------
__global__ __launch_bounds__(256) void k_wx2p(const float* __restrict__ pw,
                                              const float* __restrict__ fw,
                                              unsigned short* __restrict__ Wpp,
                                              unsigned short* __restrict__ Wfp) {
  int t = blockIdx.x * 256 + threadIdx.x;
  if (t < 16384) {
    int j = t & 7;
    int n = (t >> 3) & 127;
    int s = t >> 10;            // 0..15
    int k = (s >> 2) * 32 + (s & 3) * 8 + j;
    Wpp[t] = f2bf(pw[(size_t)k * 128 + n]);
  }
  if (t < 8192) {
    int j = t & 7;
    int n = (t >> 3) & 127;
    int s = t >> 10;            // 0..7
    int k = (s >> 2) * 32 + (s & 3) * 8 + j;
    Wfp[t] = f2bf(fw[(size_t)k * 128 + n]);
  }
}

// ---------------------------------------------------------------------------
// K-QPROJ: out[rows,128] = A[rows,64] @ W[64,128], MFMA bf16. Whole weight
// tile (16KB = 1024 short8) staged in LDS once (4 per thread); A-frags
// straight from global into registers; 16 MFMA/wave; 1 barrier.
// Used for q (53312 rows), k and v (12544 rows) projections.
// ---------------------------------------------------------------------------
__global__ __launch_bounds__(256) void k_qproj(
    const float* __restrict__ xn, const unsigned short* __restrict__ Wq,
    float* __restrict__ qb) {
  __shared__ __align__(16) unsigned short sW[8192];
  int bm = blockIdx.x * 64;
  int tid = threadIdx.x;
  int wv = tid >> 6, lane = tid & 63, quad = lane >> 4, l16 = lane & 15;

  const short8* gw = (const short8*)Wq;
  short8* dw = (short8*)sW;
#pragma unroll
  for (int i = 0; i < 4; ++i) dw[i * 256 + tid] = gw[i * 256 + tid];

  int row = bm + wv * 16 + l16;
  const float* arow = xn + (size_t)row * 64 + quad * 8;
  short8 af[2];
#pragma unroll
  for (int kc = 0; kc < 2; ++kc) {
    float4 a = *(const float4*)(arow + kc * 32);
    float4 c = *(const float4*)(arow + kc * 32 + 4);
    af[kc][0]=(short)f2bf(a.x); af[kc][1]=(short)f2bf(a.y);
    af[kc][2]=(short)f2bf(a.z); af[kc][3]=(short)f2bf(a.w);
    af[kc][4]=(short)f2bf(c.x); af[kc][5]=(short)f2bf(c.y);
    af[kc][6]=(short)f2bf(c.z); af[kc][7]=(short)f2bf(c.w);
  }
  __syncthreads();

  f32x4 acc[8];
#pragma unroll
  for (int ct = 0; ct < 8; ++ct) acc[ct] = (f32x4){0.f, 0.f, 0.f, 0.f};
#pragma unroll
  for (int kc = 0; kc < 2; ++kc) {
    int s = kc * 4 + quad;
#pragma unroll
    for (int ct = 0; ct < 8; ++ct) {
      short8 bf = *(const short8*)&sW[(s * 128 + ct * 16 + l16) << 3];
      acc[ct] = __builtin_amdgcn_mfma_f32_16x16x32_bf16(af[kc], bf, acc[ct], 0, 0, 0);
    }
  }
#pragma unroll
  for (int ct = 0; ct < 8; ++ct)
#pragma unroll
    for (int r = 0; r < 4; ++r) {
      int orow = bm + wv * 16 + quad * 4 + r;
      int col = ct * 16 + l16;
      qb[(size_t)orow * 128 + col] = acc[ct][r];
    }
}

// ---------------------------------------------------------------------------
// K-X2M (ROUND-14): fused out = xd@fc_w + fc_b + (ob@proj_w + proj_b),
// MFMA bf16, qproj pattern. Wpp (32KB) + Wfp (16KB) staged once in LDS
// (48KB -> 3 blocks/CU); A-frags from global regs; 48 MFMA/wave; 1 barrier.
// Epilogue op order identical to the fp32 k_x2: accF + fb + (accP + pb).
// ---------------------------------------------------------------------------
__global__ __launch_bounds__(256) void k_x2m(
    const float* __restrict__ ob, const unsigned short* __restrict__ Wpp,
    const float* __restrict__ pb,
    const float* __restrict__ xd, const unsigned short* __restrict__ Wfp,
    const float* __restrict__ fb, float* __restrict__ out) {
  __shared__ __align__(16) unsigned short sWp[16384];  // 32KB, 2048 short8
  __shared__ __align__(16) unsigned short sWf[8192];   // 16KB, 1024 short8
  int bm = blockIdx.x * 64;
  int tid = threadIdx.x;
  int wv = tid >> 6, lane = tid & 63, quad = lane >> 4, l16 = lane & 15;

  const short8* gp = (const short8*)Wpp;
  const short8* gf = (const short8*)Wfp;
  short8* dp = (short8*)sWp;
  short8* df = (short8*)sWf;
#pragma unroll
  for (int i = 0; i < 8; ++i) dp[i * 256 + tid] = gp[i * 256 + tid];
#pragma unroll
  for (int i = 0; i < 4; ++i) df[i * 256 + tid] = gf[i * 256 + tid];

  int row = bm + wv * 16 + l16;
  // A-frags: ob row (128 cols -> 4 frags), xd row (64 cols -> 2 frags)
  const float* orow_p = ob + (size_t)row * 128 + quad * 8;
  short8 afP[4];
#pragma unroll
  for (int kc = 0; kc < 4; ++kc) {
    float4 a = *(const float4*)(orow_p + kc * 32);
    float4 c = *(const float4*)(orow_p + kc * 32 + 4);
    afP[kc][0]=(short)f2bf(a.x); afP[kc][1]=(short)f2bf(a.y);
    afP[kc][2]=(short)f2bf(a.z); afP[kc][3]=(short)f2bf(a.w);
    afP[kc][4]=(short)f2bf(c.x); afP[kc][5]=(short)f2bf(c.y);
    afP[kc][6]=(short)f2bf(c.z); afP[kc][7]=(short)f2bf(c.w);
  }
  const float* xrow = xd + (size_t)row * 64 + quad * 8;
  short8 afF[2];
#pragma unroll
  for (int kc = 0; kc < 2; ++kc) {
    float4 a = *(const float4*)(xrow + kc * 32);
    float4 c = *(const float4*)(xrow + kc * 32 + 4);
    afF[kc][0]=(short)f2bf(a.x); afF[kc][1]=(short)f2bf(a.y);
    afF[kc][2]=(short)f2bf(a.z); afF[kc][3]=(short)f2bf(a.w);
    afF[kc][4]=(short)f2bf(c.x); afF[kc][5]=(short)f2bf(c.y);
    afF[kc][6]=(short)f2bf(c.z); afF[kc][7]=(short)f2bf(c.w);
  }
  __syncthreads();

  f32x4 accP[8];
#pragma unroll
  for (int ct = 0; ct < 8; ++ct) accP[ct] = (f32x4){0.f, 0.f, 0.f, 0.f};
#pragma unroll
  for (int kc = 0; kc < 4; ++kc) {
    int s = kc * 4 + quad;
#pragma unroll
    for (int ct = 0; ct < 8; ++ct) {
      short8 bf = *(const short8*)&sWp[(s * 128 + ct * 16 + l16) << 3];
      accP[ct] = __builtin_amdgcn_mfma_f32_16x16x32_bf16(afP[kc], bf, accP[ct], 0, 0, 0);
    }
  }
  f32x4 accF[8];
#pragma unroll
  for (int ct = 0; ct < 8; ++ct) accF[ct] = (f32x4){0.f, 0.f, 0.f, 0.f};
#pragma unroll
  for (int kc = 0; kc < 2; ++kc) {
    int s = kc * 4 + quad;
#pragma unroll
    for (int ct = 0; ct < 8; ++ct) {
      short8 bf = *(const short8*)&sWf[(s * 128 + ct * 16 + l16) << 3];
      accF[ct] = __builtin_amdgcn_mfma_f32_16x16x32_bf16(afF[kc], bf, accF[ct], 0, 0, 0);
    }
  }
#pragma unroll
  for (int ct = 0; ct < 8; ++ct)
#pragma unroll
    for (int r = 0; r < 4; ++r) {
      int orow = bm + wv * 16 + quad * 4 + r;
      int col = ct * 16 + l16;
      out[(size_t)orow * 128 + col] = accF[ct][r] + fb[col] + (accP[ct][r] + pb[col]);
    }
}

// ---------------------------------------------------------------------------
// K-CONV: xs_n = LN64(P @ wt + sr_b) -- LN fused into epilogue.
// ---------------------------------------------------------------------------
__global__ __launch_bounds__(256) void k_conv(
    const float* __restrict__ P, const unsigned short* __restrict__ Wcp,
    const float* __restrict__ bias, const float* __restrict__ sg,
    const float* __restrict__ sb, float* __restrict__ xsn) {
  __shared__ __align__(16) unsigned short sA[64 * 128];
  __shared__ __align__(16) unsigned short sW[8192];
  int bm = blockIdx.x * 64;
  int tid = threadIdx.x;
  int wv = tid >> 6, lane = tid & 63, quad = lane >> 4, l16 = lane & 15;

  const short8* gw = (const short8*)Wcp;
  short8* dw = (short8*)sW;

  short8 rw[4];
  float4 fa[4][2];
#pragma unroll
  for (int i = 0; i < 4; ++i) rw[i] = gw[i * 256 + tid];
#pragma unroll
  for (int i = 0; i < 4; ++i) {
    int u = i * 256 + tid;
    int row = u >> 4, ck = u & 15;
    const float* src = P + (size_t)(bm + row) * 1024 + ck * 8;
    fa[i][0] = *(const float4*)src;
    fa[i][1] = *(const float4*)(src + 4);
  }

  f32x4 acc[4];
#pragma unroll
  for (int ct = 0; ct < 4; ++ct) acc[ct] = (f32x4){0.f, 0.f, 0.f, 0.f};

  for (int ch = 0; ch < 8; ++ch) {
#pragma unroll
    for (int i = 0; i < 4; ++i) {
      dw[i * 256 + tid] = rw[i];
      int u = i * 256 + tid;
      int row = u >> 4, ck = u & 15;
      short8 p;
      p[0]=(short)f2bf(fa[i][0].x); p[1]=(short)f2bf(fa[i][0].y);
      p[2]=(short)f2bf(fa[i][0].z); p[3]=(short)f2bf(fa[i][0].w);
      p[4]=(short)f2bf(fa[i][1].x); p[5]=(short)f2bf(fa[i][1].y);
      p[6]=(short)f2bf(fa[i][1].z); p[7]=(short)f2bf(fa[i][1].w);
      *(short8*)&sA[row * 128 + (((ck ^ row) & 15) << 3)] = p;
    }
    __syncthreads();   // chunk visible
    if (ch < 7) {
      int wbase = (ch + 1) * 1024;
#pragma unroll
      for (int i = 0; i < 4; ++i) rw[i] = gw[wbase + i * 256 + tid];
#pragma unroll
      for (int i = 0; i < 4; ++i) {
        int u = i * 256 + tid;
        int row = u >> 4, ck = u & 15;
        const float* src = P + (size_t)(bm + row) * 1024 + (ch + 1) * 128 + ck * 8;
        fa[i][0] = *(const float4*)src;
        fa[i][1] = *(const float4*)(src + 4);
      }
    }
#pragma unroll
    for (int kc = 0; kc < 4; ++kc) {
      int row = wv * 16 + l16;
      int ck = kc * 4 + quad;
      short8 af = *(const short8*)&sA[row * 128 + (((ck ^ row) & 15) << 3)];
      int s = kc * 4 + quad;
#pragma unroll
      for (int ct = 0; ct < 4; ++ct) {
        short8 bf = *(const short8*)&sW[(s * 64 + ct * 16 + l16) << 3];
        acc[ct] = __builtin_amdgcn_mfma_f32_16x16x32_bf16(af, bf, acc[ct], 0, 0, 0);
      }
    }
    __syncthreads();   // all waves done reading before next commit
  }
  // epilogue: + bias, fused LN64, write xs_n
  float vv[4][4];
  float rsum[4], rss[4];
#pragma unroll
  for (int r = 0; r < 4; ++r) { rsum[r] = 0.f; rss[r] = 0.f; }
#pragma unroll
  for (int ct = 0; ct < 4; ++ct)
#pragma unroll
    for (int r = 0; r < 4; ++r) {
      float v = acc[ct][r] + bias[ct * 16 + l16];
      vv[ct][r] = v;
      rsum[r] += v;
      rss[r] += v * v;
    }
#pragma unroll
  for (int m = 1; m < 16; m <<= 1)
#pragma unroll
    for (int r = 0; r < 4; ++r) {
      rsum[r] += __shfl_xor(rsum[r], m);
      rss[r]  += __shfl_xor(rss[r], m);
    }
  float mean[4], rsl[4];
#pragma unroll
  for (int r = 0; r < 4; ++r) {
    mean[r] = rsum[r] * (1.f/64.f);
    float var = rss[r] * (1.f/64.f) - mean[r] * mean[r];
    rsl[r] = rsqrtf(var + LN_EPS);
  }
#pragma unroll
  for (int ct = 0; ct < 4; ++ct)
#pragma unroll
    for (int r = 0; r < 4; ++r) {
      int row = bm + wv * 16 + quad * 4 + r;
      int col = ct * 16 + l16;
      xsn[(size_t)row * 64 + col] = (vv[ct][r] - mean[r]) * rsl[r] * sg[col] + sb[col];
    }
}

// ---------------------------------------------------------------------------
// K-MLP (round-10 form; stable 61.7us local floor -- do not touch).
// out += gelu(LN128(out)@W1+b1)@W2+b2, LN fused, A-frags in registers.
// ---------------------------------------------------------------------------
__global__ __launch_bounds__(512) void k_mlp(
    const float* __restrict__ A, const float* __restrict__ gg, const float* __restrict__ gb,
    const unsigned short* __restrict__ W1q, const float* __restrict__ b1,
    const unsigned short* __restrict__ W2q, const float* __restrict__ b2,
    float* __restrict__ out) {
  __shared__ __align__(16) unsigned short sW1[8192];
  __shared__ __align__(16) unsigned short sW2[8192];
  __shared__ __align__(16) unsigned short sH[8][16 * 64];
  int bm = blockIdx.x * 128;
  int tid = threadIdx.x;
  int wv = tid >> 6, lane = tid & 63, quad = lane >> 4, l16 = lane & 15;

  const short8* g1 = (const short8*)W1q;
  const short8* g2 = (const short8*)W2q;
  short8* d1 = (short8*)sW1;
  short8* d2 = (short8*)sW2;

  short8 r1[2], r2[2];
#pragma unroll
  for (int i = 0; i < 2; ++i) {
    r1[i] = g1[i * 512 + tid];
    r2[i] = g2[i * 512 + tid];
  }

  int row = bm + wv * 16 + l16;
  int rowc = row < NROW ? row : NROW - 1;
  const float* arow = A + (size_t)rowc * 128 + quad * 8;
  float av[4][8];
  float s = 0.f, ss = 0.f;
#pragma unroll
  for (int kc = 0; kc < 4; ++kc) {
    float4 a = *(const float4*)(arow + kc * 32);
    float4 c = *(const float4*)(arow + kc * 32 + 4);
    av[kc][0]=a.x; av[kc][1]=a.y; av[kc][2]=a.z; av[kc][3]=a.w;
    av[kc][4]=c.x; av[kc][5]=c.y; av[kc][6]=c.z; av[kc][7]=c.w;
    s += a.x+a.y+a.z+a.w + c.x+c.y+c.z+c.w;
    ss += a.x*a.x+a.y*a.y+a.z*a.z+a.w*a.w + c.x*c.x+c.y*c.y+c.z*c.z+c.w*c.w;
  }
  s += __shfl_xor(s, 16);  ss += __shfl_xor(ss, 16);
  s += __shfl_xor(s, 32);  ss += __shfl_xor(ss, 32);
  float m = s * (1.f/128.f);
  float var = ss * (1.f/128.f) - m * m;
  float rs = rsqrtf(var + LN_EPS);
  short8 af[4];
#pragma unroll
  for (int kc = 0; kc < 4; ++kc) {
    int c0 = kc * 32 + quad * 8;
    float4 ga = *(const float4*)(gg + c0);
    float4 gc = *(const float4*)(gg + c0 + 4);
    float4 ba = *(const float4*)(gb + c0);
    float4 bc = *(const float4*)(gb + c0 + 4);
    af[kc][0] = (short)f2bf((av[kc][0]-m)*rs*ga.x + ba.x);
    af[kc][1] = (short)f2bf((av[kc][1]-m)*rs*ga.y + ba.y);
    af[kc][2] = (short)f2bf((av[kc][2]-m)*rs*ga.z + ba.z);
    af[kc][3] = (short)f2bf((av[kc][3]-m)*rs*ga.w + ba.w);
    af[kc][4] = (short)f2bf((av[kc][4]-m)*rs*gc.x + bc.x);
    af[kc][5] = (short)f2bf((av[kc][5]-m)*rs*gc.y + bc.y);
    af[kc][6] = (short)f2bf((av[kc][6]-m)*rs*gc.z + bc.z);
    af[kc][7] = (short)f2bf((av[kc][7]-m)*rs*gc.w + bc.w);
  }

  f32x4 oacc[8];
#pragma unroll
  for (int ct = 0; ct < 8; ++ct) oacc[ct] = (f32x4){0.f, 0.f, 0.f, 0.f};

  for (int hh = 0; hh < 8; ++hh) {
#pragma unroll
    for (int i = 0; i < 2; ++i) {
      d1[i * 512 + tid] = r1[i];
      d2[i * 512 + tid] = r2[i];
    }
    __syncthreads();
    if (hh < 7) {
      int base = (hh + 1) * 1024;
#pragma unroll
      for (int i = 0; i < 2; ++i) {
        r1[i] = g1[base + i * 512 + tid];
        r2[i] = g2[base + i * 512 + tid];
      }
    }
    f32x4 acc1[4];
#pragma unroll
    for (int ct = 0; ct < 4; ++ct) acc1[ct] = (f32x4){0.f, 0.f, 0.f, 0.f};
#pragma unroll
    for (int kc = 0; kc < 4; ++kc) {
      int sidx = kc * 4 + quad;
#pragma unroll
      for (int ct = 0; ct < 4; ++ct) {
        short8 bf = *(const short8*)&sW1[(sidx * 64 + ct * 16 + l16) << 3];
        acc1[ct] = __builtin_amdgcn_mfma_f32_16x16x32_bf16(af[kc], bf, acc1[ct], 0, 0, 0);
      }
    }
#pragma unroll
    for (int ct = 0; ct < 4; ++ct)
#pragma unroll
      for (int r = 0; r < 4; ++r) {
        float v = acc1[ct][r] + b1[hh * 64 + ct * 16 + l16];
        v = gelu_fast(v);
        int rit = quad * 4 + r;
        int col = ct * 16 + l16;
        int ck = (col >> 3) ^ (rit & 7);
        sH[wv][rit * 64 + ((ck & 7) << 3) + (col & 7)] = f2bf(v);
      }
#pragma unroll
    for (int kg = 0; kg < 2; ++kg) {
      int ckh = kg * 4 + quad;
      short8 hf = *(const short8*)&sH[wv][l16 * 64 + (((ckh ^ (l16 & 7)) & 7) << 3)];
      int sidx = kg * 4 + quad;
#pragma unroll
      for (int ct = 0; ct < 8; ++ct) {
        short8 bf = *(const short8*)&sW2[(sidx * 128 + ct * 16 + l16) << 3];
        oacc[ct] = __builtin_amdgcn_mfma_f32_16x16x32_bf16(hf, bf, oacc[ct], 0, 0, 0);
      }
    }
    __syncthreads();
  }
#pragma unroll
  for (int ct = 0; ct < 8; ++ct)
#pragma unroll
    for (int r = 0; r < 4; ++r) {
      int orow = bm + wv * 16 + quad * 4 + r;
      int col = ct * 16 + l16;
      if (orow < NROW)
        out[(size_t)orow * 128 + col] += oacc[ct][r] + b2[col];
    }
}

// ---------------------------------------------------------------------------
// K7: MFMA attention (round-10 form: 31KB LDS, high residency).
// ---------------------------------------------------------------------------
__global__ __launch_bounds__(256) void k_attn(const float* __restrict__ q,
    const float* __restrict__ kg, const float* __restrict__ vg, float* __restrict__ o) {
  __shared__ __align__(16) unsigned short ldsKP[14848];
  __shared__ __align__(16) unsigned short ldsV[16128];
  int blk = blockIdx.x;
  int chunk = blk % 14;
  int bh = blk / 14;
  int h = bh & 1, b = bh >> 1;
  int tid = threadIdx.x;
  int wv = tid >> 6, lane = tid & 63;
  int quad = lane >> 4, l16 = lane & 15;

  const float* kb = kg + (size_t)b * NS * 128 + h * 64;
  const float* vb = vg + (size_t)b * NS * 128 + h * 64;

  for (int t = tid; t < KPAD * 8; t += 256) {
    int key = t >> 3, ck = t & 7;
    short8 pk, pv;
    if (key < NS) {
      const float* ksrc = kb + (size_t)key * 128 + ck * 8;
      const float* vsrc = vb + (size_t)key * 128 + ck * 8;
      float4 a = *(const float4*)ksrc;
      float4 c = *(const float4*)(ksrc + 4);
      pk[0]=(short)f2bf(a.x); pk[1]=(short)f2bf(a.y); pk[2]=(short)f2bf(a.z); pk[3]=(short)f2bf(a.w);
      pk[4]=(short)f2bf(c.x); pk[5]=(short)f2bf(c.y); pk[6]=(short)f2bf(c.z); pk[7]=(short)f2bf(c.w);
      float4 e = *(const float4*)vsrc;
      float4 g = *(const float4*)(vsrc + 4);
      pv[0]=(short)f2bf(e.x); pv[1]=(short)f2bf(e.y); pv[2]=(short)f2bf(e.z); pv[3]=(short)f2bf(e.w);
      pv[4]=(short)f2bf(g.x); pv[5]=(short)f2bf(g.y); pv[6]=(short)f2bf(g.z); pv[7]=(short)f2bf(g.w);
    } else {
      pk = (short8)0; pv = (short8)0;
    }
    *(short8*)&ldsKP[key * 64 + ((ck ^ (key & 7)) << 3)] = pk;
    *(short8*)&ldsV[key * 72 + ck * 8] = pv;
  }

  int qrow = chunk * 64 + wv * 16 + l16;
  int qrowc = qrow < ND ? qrow : ND - 1;
  const float* qsrc = q + ((size_t)b * ND + qrowc) * 128 + h * 64 + quad * 8;
  short8 aq0, aq1;
  {
    float4 a = *(const float4*)qsrc;
    float4 c = *(const float4*)(qsrc + 4);
    aq0[0]=(short)f2bf(a.x); aq0[1]=(short)f2bf(a.y); aq0[2]=(short)f2bf(a.z); aq0[3]=(short)f2bf(a.w);
    aq0[4]=(short)f2bf(c.x); aq0[5]=(short)f2bf(c.y); aq0[6]=(short)f2bf(c.z); aq0[7]=(short)f2bf(c.w);
    float4 e = *(const float4*)(qsrc + 32);
    float4 g = *(const float4*)(qsrc + 36);
    aq1[0]=(short)f2bf(e.x); aq1[1]=(short)f2bf(e.y); aq1[2]=(short)f2bf(e.z); aq1[3]=(short)f2bf(e.w);
    aq1[4]=(short)f2bf(g.x); aq1[5]=(short)f2bf(g.y); aq1[6]=(short)f2bf(g.z); aq1[7]=(short)f2bf(g.w);
  }
  __syncthreads();

  f32x4 acc[14];
#pragma unroll
  for (int ct = 0; ct < 14; ++ct) {
    int key = ct * 16 + l16;
    short8 bk0 = *(const short8*)&ldsKP[key * 64 + ((quad ^ (key & 7)) << 3)];
    short8 bk1 = *(const short8*)&ldsKP[key * 64 + (((4 + quad) ^ (key & 7)) << 3)];
    f32x4 z = {0.f, 0.f, 0.f, 0.f};
    z = __builtin_amdgcn_mfma_f32_16x16x32_bf16(aq0, bk0, z, 0, 0, 0);
    z = __builtin_amdgcn_mfma_f32_16x16x32_bf16(aq1, bk1, z, 0, 0, 0);
    acc[ct] = z;
  }

  const float scale = 0.17677669529663687f;  // 32^-0.5
  float rmax[4] = {-1e30f, -1e30f, -1e30f, -1e30f};
#pragma unroll
  for (int ct = 0; ct < 14; ++ct) {
    bool msk = (ct * 16 + l16) >= NS;
#pragma unroll
    for (int r = 0; r < 4; ++r) {
      float sv = msk ? -1e30f : acc[ct][r] * scale;
      acc[ct][r] = sv;
      rmax[r] = fmaxf(rmax[r], sv);
    }
  }
#pragma unroll
  for (int m = 1; m < 16; m <<= 1)
#pragma unroll
    for (int r = 0; r < 4; ++r) rmax[r] = fmaxf(rmax[r], __shfl_xor(rmax[r], m));
  float rsum[4] = {0.f, 0.f, 0.f, 0.f};
#pragma unroll
  for (int ct = 0; ct < 14; ++ct)
#pragma unroll
    for (int r = 0; r < 4; ++r) {
      float e = __expf(acc[ct][r] - rmax[r]);
      acc[ct][r] = e;
      rsum[r] += e;
    }
#pragma unroll
  for (int m = 1; m < 16; m <<= 1)
#pragma unroll
    for (int r = 0; r < 4; ++r) rsum[r] += __shfl_xor(rsum[r], m);
  float rinv[4];
#pragma unroll
  for (int r = 0; r < 4; ++r) rinv[r] = 1.f / rsum[r];

  __syncthreads();

#pragma unroll
  for (int ct = 0; ct < 14; ++ct)
#pragma unroll
    for (int r = 0; r < 4; ++r) {
      int prow = wv * 16 + quad * 4 + r;
      ldsKP[prow * 232 + ct * 16 + l16] = f2bf(acc[ct][r] * rinv[r]);
    }
  __syncthreads();

  f32x4 oacc[4];
#pragma unroll
  for (int ot = 0; ot < 4; ++ot) oacc[ot] = (f32x4){0.f, 0.f, 0.f, 0.f};
#pragma unroll
  for (int kc = 0; kc < 7; ++kc) {
    short8 ap = *(const short8*)&ldsKP[(wv * 16 + l16) * 232 + kc * 32 + quad * 8];
    int keybase = kc * 32 + quad * 8;
#pragma unroll
    for (int ot = 0; ot < 4; ++ot) {
      int dcol = ot * 16 + l16;
      short8 bv;
#pragma unroll
      for (int j = 0; j < 8; ++j) bv[j] = (short)ldsV[(keybase + j) * 72 + dcol];
      oacc[ot] = __builtin_amdgcn_mfma_f32_16x16x32_bf16(ap, bv, oacc[ot], 0, 0, 0);
    }
  }

#pragma unroll
  for (int ot = 0; ot < 4; ++ot)
#pragma unroll
    for (int r = 0; r < 4; ++r) {
      int rowg = chunk * 64 + wv * 16 + quad * 4 + r;
      if (rowg < ND)
        o[((size_t)b * ND + rowg) * 128 + h * 64 + ot * 16 + l16] = oacc[ot][r];
    }
}

// ---------------------------------------------------------------------------
// K8: bilinear grid-sample of pos_embed at pos_down, accumulate into out
// ---------------------------------------------------------------------------
__global__ __launch_bounds__(256) void k_posfeat(const float* __restrict__ pd,
    const float* __restrict__ pe, float* __restrict__ out) {
  int t = blockIdx.x * 256 + threadIdx.x;
  int row = t >> 5, lane = t & 31;
  if (row >= B_ * ND) return;
  float gx = pd[(size_t)2*row] * 2.f - 1.f;
  float gy = pd[(size_t)2*row+1] * 2.f - 1.f;
  float ix = ((gx + 1.f) * 56.f - 1.f) * 0.5f;
  float iy = ((gy + 1.f) * 56.f - 1.f) * 0.5f;
  float x0 = floorf(ix), y0 = floorf(iy);
  float wx1 = ix - x0, wy1 = iy - y0;
  float wx0 = 1.f - wx1, wy0 = 1.f - wy1;
  float4 acc = make_float4(0.f, 0.f, 0.f, 0.f);
#pragma unroll
  for (int cy = 0; cy < 2; ++cy) {
#pragma unroll
    for (int cx = 0; cx < 2; ++cx) {
      float xc = x0 + (float)cx, yc = y0 + (float)cy;
      float wgt = (cx ? wx1 : wx0) * (cy ? wy1 : wy0);
      bool valid = (xc >= 0.f) && (xc < 56.f) && (yc >= 0.f) && (yc < 56.f);
      if (valid) {
        int lin = (int)yc * 56 + (int)xc;
        float4 pv = ((const float4*)(pe + (size_t)lin * 128))[lane];
        acc.x += wgt * pv.x; acc.y += wgt * pv.y;
        acc.z += wgt * pv.z; acc.w += wgt * pv.w;
      }
    }
  }
  float4* op = (float4*)(out + (size_t)row * 128) + lane;
  float4 cur = *op;
  cur.x += acc.x; cur.y += acc.y; cur.z += acc.z; cur.w += acc.w;
  *op = cur;
}

// ---------------------------------------------------------------------------
// launcher
// ---------------------------------------------------------------------------
extern "C" void kernel_launch(void* const* d_in, const int* in_sizes, int n_in,
                              void* d_out, int out_size, void* d_ws, size_t ws_size,
                              hipStream_t stream) {
  const float* x      = (const float*)d_in[0];
  const float* pos    = (const float*)d_in[1];
  const float* pe     = (const float*)d_in[2];
  const float* nu     = (const float*)d_in[3];
  const float* norm_g = (const float*)d_in[4];
  const float* norm_b = (const float*)d_in[5];
  const float* conf_w = (const float*)d_in[6];
  const float* conf_b = (const float*)d_in[7];
  const float* n1g    = (const float*)d_in[8];
  const float* n1b    = (const float*)d_in[9];
  const float* q_w    = (const float*)d_in[10];
  const float* k_w    = (const float*)d_in[11];
  const float* v_w    = (const float*)d_in[12];
  const float* proj_w = (const float*)d_in[13];
  const float* proj_b = (const float*)d_in[14];
  const float* sr_w   = (const float*)d_in[15];
  const float* sr_b   = (const float*)d_in[16];
  const float* srn_g  = (const float*)d_in[17];
  const float* srn_b  = (const float*)d_in[18];
  const float* fc_w   = (const float*)d_in[19];
  const float* fc_b   = (const float*)d_in[20];
  const float* n2g    = (const float*)d_in[21];
  const float* n2b    = (const float*)d_in[22];
  const float* fc1_w  = (const float*)d_in[23];
  const float* fc1_b  = (const float*)d_in[24];
  const float* fc2_w  = (const float*)d_in[25];
  const float* fc2_b  = (const float*)d_in[26];

  char* ws = (char*)d_ws;
  // workspace layout (bytes); total 190,578,688 (unchanged)
  double*         scores = (double*)(ws + 0);                //  1,580,544
  int*            idx    = (int*)(ws + 1605632);             //    200,704
  float*          xd     = (float*)(ws + 1835008);           // 13,647,872
  float*          xn     = (float*)(ws + 15728640);          // 13,647,872
  float*          pd     = (float*)(ws + 29491200);          //    426,496
  float*          qb     = (float*)(ws + 30408704);          // 27,295,744; T alias; later q
  float*          ob     = (float*)(ws + 58720256);          // 27,295,744; T tail alias
  unsigned short* Wcp    = (unsigned short*)(ws + 86507520); //    131,072 (conv weights, bf16 packed)
  unsigned short* W1p    = (unsigned short*)(ws + 86769664); //    131,072
  unsigned short* W2p    = (unsigned short*)(ws + 86900736); //    131,072 (ends 87,031,808)
  char*           big    = ws + 87031808;                    // 103,546,880 region
  float*          S      = (float*)big;                      // 52,183,040 (dead after transpose)
  float*          T      = qb;                               // 51,380,224 channel planes (dead after filter2)
  float*          Kc     = (float*)(big + 52183040);         //  7,225,344 coefficient planes (dead after filter2)
  float*          P      = (float*)big;                      // 51,380,224 (reuses dead S; dead after conv)
  float*          xs_n   = (float*)(big + 62619648);         //  3,211,264
  float*          kbuf   = (float*)(big + 65830912);         //  6,422,528
  float*          vbuf   = (float*)(big + 72253440);         //  6,422,528 (ends 78,675,968)
  float*          Mbuf   = (float*)(big + 78675968);         //    802,816 mask plane (dead after coef)
  int*            head   = (int*)(big + 79478784);           //    802,816 (dead after accum)
  int*            nxt    = (int*)(big + 80281600);           //    802,816 (ends 81,084,416)
  unsigned short* Wqp    = (unsigned short*)(big + 81084416);//     16,384 (q_w packed)
  unsigned short* Wkp    = (unsigned short*)(big + 81100800);//     16,384 (k_w packed)
  unsigned short* Wvp    = (unsigned short*)(big + 81117184);//     16,384 (v_w packed)
  unsigned short* Wpp    = (unsigned short*)(big + 81133568);//     32,768 (proj_w packed)
  unsigned short* Wfp    = (unsigned short*)(big + 81166336);//     16,384 (fc_w packed; ends 81,182,720)
  float*          out    = (float*)d_out;

  // 1) f64 conf+gumbel scores
  k_conf<<<(B_ * N_) / 256, 256, 0, stream>>>(x, norm_g, norm_b, conf_w, conf_b, nu, scores);
  // 2) top-784 per batch: exact counting-sort rank (one block per batch)
  k_topk2<<<B_, 256, 0, stream>>>(scores, idx);
  // 3) gather + LN(norm1)
  k_gather_ln<<<(B_ * ND + 255) / 256, 256, 0, stream>>>(x, pos, idx, n1g, n1b, xd, xn, pd);
  // 4) token2map: per-pixel linked lists then gather-accumulate
  hipMemsetAsync(head, 0xFF, (size_t)B_ * HW * sizeof(int), stream);
  k_link<<<(B_ * N_ + 255) / 256, 256, 0, stream>>>(pos, head, nxt);
  k_accum<<<(B_ * HW * 64) / 256, 256, 0, stream>>>(x, n1g, n1b, head, nxt, S);
  // 5) gaussian reconstruct: transpose (+mask plane), coef, 3x3 conv
  k_transpose<<<BHW / 64, 256, 0, stream>>>(S, T, Mbuf);
  k_coef<<<BHW / 256, 256, 0, stream>>>(Mbuf, Kc);
  k_filter2<<<B_ * 64, 256, 0, stream>>>(T, Kc, P);
  // 6) weight packing; MFMA conv-as-GEMM with fused LN64
  k_wtp<<<65536 / 256, 256, 0, stream>>>(sr_w, Wcp);
  k_wpack<<<65536 / 256, 256, 0, stream>>>(fc1_w, fc2_w, W1p, W2p);
  k_wqp<<<8192 / 256, 256, 0, stream>>>(q_w, Wqp);
  k_wqp<<<8192 / 256, 256, 0, stream>>>(k_w, Wkp);
  k_wqp<<<8192 / 256, 256, 0, stream>>>(v_w, Wvp);
  k_wx2p<<<16384 / 256, 256, 0, stream>>>(proj_w, fc_w, Wpp, Wfp);
  k_conv<<<B_ * NS / 64, 256, 0, stream>>>(P, Wcp, sr_b, srn_g, srn_b, xs_n);
  // 7) k, v, q projections -- all MFMA via k_qproj
  k_qproj<<<B_ * NS / 64, 256, 0, stream>>>(xs_n, Wkp, kbuf);
  k_qproj<<<B_ * NS / 64, 256, 0, stream>>>(xs_n, Wvp, vbuf);
  k_qproj<<<NROW / 64, 256, 0, stream>>>(xn, Wqp, qb);
  // 8) attention (MFMA bf16)
  k_attn<<<B_ * 2 * 14, 256, 0, stream>>>(qb, kbuf, vbuf, ob);
  // 9) fused x2 = xd@fc_w + fc_b + (ob@proj_w + proj_b) -> d_out (MFMA)
  k_x2m<<<NROW / 64, 256, 0, stream>>>(ob, Wpp, proj_b, xd, Wfp, fc_b, out);
  // 10) MLP: fused LN128 + fc1 + gelu + fc2 (128-row 8-wave blocks)
  k_mlp<<<(NROW + 127) / 128, 512, 0, stream>>>(out, n2g, n2b, W1p, fc1_b, W2p, fc2_b, out);
  // 11) + pos_feat (bilinear grid sample)
  k_posfeat<<<(B_ * ND * 32) / 256, 256, 0, stream>>>(pd, pe, out);
}